// Round 5
// baseline (445.623 us; speedup 1.0000x reference)
//
#include <hip/hip_runtime.h>
#include <stdint.h>

// Problem constants (fixed by setup_inputs)
constexpr int B   = 2;
constexpr int T   = 2048;
constexpr int D   = 2048;
constexpr int H   = 32;
constexpr int KVH = 8;
constexpr int HD  = 64;          // head dim
constexpr int R   = B * T;       // 4096 rows
constexpr int OKV = KVH * HD;    // 512

using bf16x8 = __attribute__((ext_vector_type(8))) __bf16;
using f32x4  = __attribute__((ext_vector_type(4))) float;
using i32x4  = __attribute__((ext_vector_type(4))) int;

__device__ inline float fast_exp2(float x) {
#if __has_builtin(__builtin_amdgcn_exp2f)
    return __builtin_amdgcn_exp2f(x);    // v_exp_f32: computes 2^x
#else
    return exp2f(x);
#endif
}

__device__ inline uint16_t f2bf(float f) {
    uint32_t u = __float_as_uint(f);
    u += 0x7fff + ((u >> 16) & 1);   // RNE
    return (uint16_t)(u >> 16);
}

__device__ inline uint32_t pack_bf16(float a, float b) {
#if __has_builtin(__builtin_amdgcn_cvt_pk_bf16_f32)
    union { __attribute__((ext_vector_type(2))) __bf16 v; uint32_t u; } r;
    r.v = __builtin_amdgcn_cvt_pk_bf16_f32(a, b);
    return r.u;
#else
    return (uint32_t)f2bf(a) | ((uint32_t)f2bf(b) << 16);
#endif
}

// async global->LDS, 16B per lane; LDS dest = (wave-uniform) base + lane*16
__device__ inline void async16(const void* g, void* l) {
    __builtin_amdgcn_global_load_lds((const __attribute__((address_space(1))) unsigned int*)g,
                                     (__attribute__((address_space(3))) unsigned int*)l,
                                     16, 0, 0);
}

// ---------------- weight scales: mean(|w|), all 4 weights in one launch --------
__global__ void absmean4_kernel(const float* __restrict__ w0, const float* __restrict__ w1,
                                const float* __restrict__ w2, const float* __restrict__ w3,
                                double* __restrict__ sums) {
    __shared__ float red[256];
    const float* ws[4] = {w0, w1, w2, w3};
    const int ns[4] = {D * D, OKV * D, OKV * D, D * D};
    int wi = blockIdx.y;
    const float* w = ws[wi];
    int n = ns[wi];
    int tid = threadIdx.x;
    float s = 0.f;
    for (int i = blockIdx.x * 256 + tid; i < n; i += gridDim.x * 256)
        s += fabsf(w[i]);
    red[tid] = s;
    __syncthreads();
    for (int st = 128; st > 0; st >>= 1) {
        if (tid < st) red[tid] += red[tid + st];
        __syncthreads();
    }
    if (tid == 0) atomicAdd(&sums[wi], (double)red[0]);
}

// ---------------- ternary weight quantization, all 4 in one launch ----------------
__global__ void quantw4_kernel(const float* __restrict__ w0, const float* __restrict__ w1,
                               const float* __restrict__ w2, const float* __restrict__ w3,
                               int8_t* __restrict__ o0, int8_t* __restrict__ o1,
                               int8_t* __restrict__ o2, int8_t* __restrict__ o3,
                               const double* __restrict__ sums) {
    const float* ws[4] = {w0, w1, w2, w3};
    int8_t* os[4] = {o0, o1, o2, o3};
    const int ns[4] = {D * D, OKV * D, OKV * D, D * D};
    int wi = blockIdx.y;
    const float* w = ws[wi];
    int8_t* o = os[wi];
    int n = ns[wi];
    float wsc = fmaxf((float)(sums[wi] / (double)n), 1e-5f);
    for (int i = blockIdx.x * 256 + threadIdx.x; i < n; i += gridDim.x * 256) {
        float q = rintf(w[i] / wsc);
        q = fminf(fmaxf(q, -1.f), 1.f);
        o[i] = (int8_t)q;
    }
}

// ---------------- fused rmsnorm + absmax int8 quant for q,k,v ----------------
__global__ __launch_bounds__(256) void rmsq3_kernel(const float* __restrict__ X,
        const float* __restrict__ g0, const float* __restrict__ g1, const float* __restrict__ g2,
        int8_t* __restrict__ o0, int8_t* __restrict__ o1, int8_t* __restrict__ o2,
        float* __restrict__ s0, float* __restrict__ s1, float* __restrict__ s2) {
    __shared__ float red[256];
    int row = blockIdx.x, tid = threadIdx.x;
    const float* xr = X + (size_t)row * D;
    float xv[8];
    float ss = 0.f;
#pragma unroll
    for (int i = 0; i < 8; i++) { xv[i] = xr[tid + 256 * i]; ss += xv[i] * xv[i]; }
    red[tid] = ss;
    __syncthreads();
    for (int st = 128; st > 0; st >>= 1) {
        if (tid < st) red[tid] += red[tid + st];
        __syncthreads();
    }
    float rstd = 1.0f / sqrtf(red[0] / (float)D + 1e-6f);

    const float* gs[3] = {g0, g1, g2};
    int8_t* os[3] = {o0, o1, o2};
    float* sc[3] = {s0, s1, s2};
#pragma unroll
    for (int v = 0; v < 3; v++) {
        float xn[8];
        float amax = 0.f;
#pragma unroll
        for (int i = 0; i < 8; i++) {
            xn[i] = xv[i] * rstd * gs[v][tid + 256 * i];
            amax = fmaxf(amax, fabsf(xn[i]));
        }
        __syncthreads();
        red[tid] = amax;
        __syncthreads();
        for (int st = 128; st > 0; st >>= 1) {
            if (tid < st) red[tid] = fmaxf(red[tid], red[tid + st]);
            __syncthreads();
        }
        float xsv = fmaxf(red[0], 1e-5f);
        float q127 = 127.0f / xsv;
#pragma unroll
        for (int i = 0; i < 8; i++) {
            float q = rintf(xn[i] * q127);
            q = fminf(fmaxf(q, -128.f), 127.f);
            os[v][(size_t)row * D + tid + 256 * i] = (int8_t)q;
        }
        if (tid == 0) sc[v][row] = xsv;
    }
}

// ---------------- rmsnorm + quant (single, for o-proj input) ----------------
// register-cached: one global read of the row, like rmsq3
__global__ __launch_bounds__(256) void rmsq_kernel(const float* __restrict__ X,
                                                   const float* __restrict__ g,
                                                   int8_t* __restrict__ Xq,
                                                   float* __restrict__ xs_out) {
    __shared__ float red[256];
    int row = blockIdx.x, tid = threadIdx.x;
    const float* xr = X + (size_t)row * D;
    float xv[8];
    float ss = 0.f;
#pragma unroll
    for (int i = 0; i < 8; i++) { xv[i] = xr[tid + 256 * i]; ss += xv[i] * xv[i]; }
    red[tid] = ss;
    __syncthreads();
    for (int st = 128; st > 0; st >>= 1) {
        if (tid < st) red[tid] += red[tid + st];
        __syncthreads();
    }
    float rstd = 1.0f / sqrtf(red[0] / (float)D + 1e-6f);

    float xn[8];
    float amax = 0.f;
#pragma unroll
    for (int i = 0; i < 8; i++) {
        xn[i] = xv[i] * rstd * g[tid + 256 * i];
        amax = fmaxf(amax, fabsf(xn[i]));
    }
    __syncthreads();
    red[tid] = amax;
    __syncthreads();
    for (int st = 128; st > 0; st >>= 1) {
        if (tid < st) red[tid] = fmaxf(red[tid], red[tid + st]);
        __syncthreads();
    }
    float xs = fmaxf(red[0], 1e-5f);
    float q127 = 127.0f / xs;
#pragma unroll
    for (int i = 0; i < 8; i++) {
        float q = rintf(xn[i] * q127);
        q = fminf(fmaxf(q, -128.f), 127.f);
        Xq[(size_t)row * D + tid + 256 * i] = (int8_t)q;
    }
    if (tid == 0) xs_out[row] = xs;
}

// ---------------- i8 MFMA GEMM, wave = 32 rows x BN cols ----------------
// MODE 0: f32 output. MODE 1: bf16 output with fused RoPE (rope partners
// col and col+32 are acc[mt][nt] / acc[mt][nt+2] in the same lane).
// MODE 2: v-proj -> transposed bf16 output vt[(b*KVH+kvh)*64+d][t]
// (fuses the old vtrans kernel: 4 consecutive tokens per lane = 8B store).
template<int BN, int MODE>
__global__ __launch_bounds__(256) void gemm_i8_mfma(const int8_t* __restrict__ Xq,
                                                    const int8_t* __restrict__ W8,
                                                    void* __restrict__ outp,
                                                    const float* __restrict__ xs,
                                                    const double* __restrict__ wsum, int wi,
                                                    int nw, int O,
                                                    const float* __restrict__ cs,
                                                    const float* __restrict__ sn) {
    constexpr int NT = BN / 16;          // n-tiles per wave (full BN span)
    __shared__ __align__(16) uint8_t As[128 * 128];
    __shared__ __align__(16) uint8_t Bs[BN * 128];

    const int tid  = threadIdx.x;
    const int lane = tid & 63;
    const int wv   = tid >> 6;
    const int n    = lane & 15, quad = lane >> 4;
    const int row0 = blockIdx.y * 128;
    const int col0 = blockIdx.x * BN;

    i32x4 acc[2][NT] = {};

    for (int k0 = 0; k0 < D; k0 += 128) {
        __syncthreads();
#pragma unroll
        for (int j = 0; j < 4; j++) {
            int p = wv * 256 + j * 64 + lane;
            int r = p >> 3, s = p & 7;
            int c = s ^ (r & 7);
            async16(Xq + (size_t)(row0 + r) * D + k0 + c * 16,
                    &As[(size_t)(wv * 256 + j * 64) * 16]);
        }
#pragma unroll
        for (int j = 0; j < BN / 32; j++) {
            int p = wv * (BN * 2) + j * 64 + lane;
            int r = p >> 3, s = p & 7;
            int c = s ^ (r & 7);
            async16(W8 + (size_t)(col0 + r) * D + k0 + c * 16,
                    &Bs[(size_t)(wv * (BN * 2) + j * 64) * 16]);
        }
        __syncthreads();
#pragma unroll
        for (int t = 0; t < 2; t++) {
            i32x4 af[2], bfr[NT];
#pragma unroll
            for (int mt = 0; mt < 2; mt++) {
                int r = wv * 32 + mt * 16 + n;
                af[mt] = *(const i32x4*)&As[r * 128 + (((t * 4 + quad) ^ (r & 7)) * 16)];
            }
#pragma unroll
            for (int nt = 0; nt < NT; nt++) {
                int r = nt * 16 + n;
                bfr[nt] = *(const i32x4*)&Bs[r * 128 + (((t * 4 + quad) ^ (r & 7)) * 16)];
            }
#pragma unroll
            for (int mt = 0; mt < 2; mt++)
#pragma unroll
                for (int nt = 0; nt < NT; nt++)
                    acc[mt][nt] = __builtin_amdgcn_mfma_i32_16x16x64_i8(af[mt], bfr[nt], acc[mt][nt], 0, 0, 0);
        }
    }
    float w = fmaxf((float)(wsum[wi] / (double)nw), 1e-5f);
#pragma unroll
    for (int mt = 0; mt < 2; mt++) {
        if (MODE == 2) {
            // transposed bf16 write: rows are 4 consecutive tokens per lane
            int rowb = row0 + wv * 32 + mt * 16 + quad * 4;
            int bb = rowb >> 11;              // rowb / T
            int tb = rowb & (T - 1);
            float fr[4];
#pragma unroll
            for (int r2 = 0; r2 < 4; r2++)
                fr[r2] = w * xs[rowb + r2] * (1.0f / 127.0f);
            uint16_t* o16 = (uint16_t*)outp;
#pragma unroll
            for (int nt = 0; nt < NT; nt++) {
                int col = col0 + nt * 16 + n;
                int kvh = col >> 6, d = col & 63;
                uint2 w2;
                w2.x = pack_bf16((float)acc[mt][nt][0] * fr[0], (float)acc[mt][nt][1] * fr[1]);
                w2.y = pack_bf16((float)acc[mt][nt][2] * fr[2], (float)acc[mt][nt][3] * fr[3]);
                *(uint2*)(o16 + ((size_t)(bb * KVH + kvh) * 64 + d) * T + tb) = w2;
            }
            continue;
        }
#pragma unroll
        for (int r2 = 0; r2 < 4; r2++) {
            int row = row0 + wv * 32 + mt * 16 + quad * 4 + r2;
            float f = w * xs[row] * (1.0f / 127.0f);
            if (MODE == 0) {
                float* out = (float*)outp;
#pragma unroll
                for (int nt = 0; nt < NT; nt++)
                    out[(size_t)row * O + col0 + nt * 16 + n] = (float)acc[mt][nt][r2] * f;
            } else {
                uint16_t* out = (uint16_t*)outp;
                int t = row & (T - 1);
#pragma unroll
                for (int nt = 0; nt < NT; nt++) {
                    if ((nt & 3) >= 2) continue;   // rope pair handled at nt, nt+2
                    int i = (nt * 16 + n) & 63;
                    float a  = (float)acc[mt][nt][r2] * f;
                    float bb = (float)acc[mt][nt + 2][r2] * f;
                    float c0 = cs[t * HD + i],      s0 = sn[t * HD + i];
                    float c1 = cs[t * HD + i + 32], s1 = sn[t * HD + i + 32];
                    out[(size_t)row * O + col0 + nt * 16 + n]       = f2bf(a * c0 - bb * s0);
                    out[(size_t)row * O + col0 + (nt + 2) * 16 + n] = f2bf(bb * c1 + a * s1);
                }
            }
        }
    }
}

// ---------------- MFMA flash attention: 8-wave blocks, 16 waves/CU ----
// grid (8, H, B) = 512 blocks, 512 threads (8 waves). Block p handles causal
// strips p and 15-p; wave wv owns 2 q-tiles: {p,15-p}*128 + wv*16. This pairing
// makes every block do exactly (2p+2)+(32-2p) = 34 tile-activations over its
// 32-2p staged chunks: perfectly balanced blocks, 2 tile-computes per staged
// chunk (r4's single-strip split halved that ratio and regressed -- keep pairs).
// Register diet keeps VGPR ~60 (no kf/vf arrays, scalar l accumulation).
// Defer-max (T13, THR=8 log2-units) + s_setprio around MFMA clusters (T5).
__global__ __launch_bounds__(512, 6) void attn_mfma_kernel(const uint16_t* __restrict__ qh,
                                                           const uint16_t* __restrict__ kh,
                                                           const uint16_t* __restrict__ vt,
                                                           float* __restrict__ out) {
    __shared__ __align__(16) uint16_t KsB[2][64 * 64];
    __shared__ __align__(16) uint16_t VtB[2][64 * 64];
    __shared__ __align__(16) uint16_t Pw[8][16 * 72];   // per-wave P [q][key] (one tile)

    const int tid  = threadIdx.x;
    const int lane = tid & 63;
    const int wv   = tid >> 6;            // 0..7
    const int p = blockIdx.x, h = blockIdx.y, b = blockIdx.z;
    const int kvh = h >> 2;               // n_rep = 4
    const int n = lane & 15, quad = lane >> 4;
    const float SC = 0.125f * 1.44269504089f;   // score -> log2 units
    const float DEFER = 44.3614f;               // 8 / SC: defer-max threshold (score units)

    // 2 q-tiles per wave: one from strip p (short), one from strip 15-p (long)
    int q_lo[2] = { p * 128 + wv * 16, (15 - p) * 128 + wv * 16 };

    bf16x8 qf[2][2];
#pragma unroll
    for (int i = 0; i < 2; i++) {
        const uint16_t* qp = qh + (size_t)(b * T + q_lo[i] + n) * D + h * HD + quad * 8;
        qf[i][0] = *(const bf16x8*)(qp);
        qf[i][1] = *(const bf16x8*)(qp + 32);
    }

    f32x4 o[2][4] = {};
    float ls[2] = { 0.f, 0.f };
    float m[2] = { -INFINITY, -INFINITY };

    const uint16_t* kbase = kh + (size_t)b * T * OKV + kvh * HD;
    const uint16_t* vbase = vt + (size_t)(b * KVH + kvh) * 64 * T;

    const int nch = 32 - 2 * p;           // chunks for the longer strip (15-p)

    // stage chunk 0 -> buf 0: 512 threads x 16B = exactly one 64x64 bf16 tile each
    {
        int r = tid >> 3, sl = tid & 7;
        int c = sl ^ (r & 7);
        async16(kbase + (size_t)r * OKV + c * 8, &KsB[0][wv * 512]);
        async16(vbase + (size_t)r * T + c * 8,   &VtB[0][wv * 512]);
    }
    __syncthreads();

    for (int ch = 0; ch < nch; ch++) {
        const int cur = ch & 1;
        if (ch + 1 < nch) {   // prefetch next chunk into alternate buffer
            const int t1 = (ch + 1) * 64;
            int r = tid >> 3, sl = tid & 7;
            int c = sl ^ (r & 7);
            async16(kbase + (size_t)(t1 + r) * OKV + c * 8, &KsB[cur ^ 1][wv * 512]);
            async16(vbase + (size_t)r * T + t1 + c * 8,     &VtB[cur ^ 1][wv * 512]);
        }
        const int t0 = ch * 64;
        const uint16_t* Ks = KsB[cur];
        const uint16_t* Vs = VtB[cur];

        // fused per-tile: QK^T -> softmax -> P roundtrip -> PV^T
#pragma unroll
        for (int i = 0; i < 2; i++) {
            if (t0 > q_lo[i] + 15) continue;
            f32x4 sv[4] = {};
            __builtin_amdgcn_s_setprio(1);
#pragma unroll
            for (int ks = 0; ks < 2; ks++)
#pragma unroll
                for (int mt = 0; mt < 4; mt++) {
                    int r = mt * 16 + n;
                    bf16x8 kfr = *(const bf16x8*)&Ks[r * 64 + (((ks * 4 + quad) ^ (n & 7)) * 8)];
                    sv[mt] = __builtin_amdgcn_mfma_f32_16x16x32_bf16(kfr, qf[i][ks], sv[mt], 0, 0, 0);
                }
            __builtin_amdgcn_s_setprio(0);

            const int qg = q_lo[i] + n;
            const bool diag = (t0 + 63 > q_lo[i]);
            float mloc = -INFINITY;
#pragma unroll
            for (int mt = 0; mt < 4; mt++)
#pragma unroll
                for (int r2 = 0; r2 < 4; r2++) {
                    float x = sv[mt][r2];
                    if (diag) {
                        int kg = t0 + mt * 16 + quad * 4 + r2;
                        x = (kg > qg) ? -INFINITY : x;
                        sv[mt][r2] = x;
                    }
                    mloc = fmaxf(mloc, x);
                }
            mloc = fmaxf(mloc, __shfl_xor(mloc, 16));
            mloc = fmaxf(mloc, __shfl_xor(mloc, 32));
            // defer-max: only pay the rescale pass when the max moved >DEFER.
            // P values then bounded by 2^8; f32 accumulation has ample headroom.
            bool upd = (mloc > m[i] + DEFER);
            if (__ballot(upd)) {
                float mnew = fmaxf(m[i], mloc);
                float corr = fast_exp2((m[i] - mnew) * SC);   // ==1 when unchanged; 0 on first chunk
                m[i] = mnew;
#pragma unroll
                for (int mt = 0; mt < 4; mt++)
#pragma unroll
                    for (int r2 = 0; r2 < 4; r2++) o[i][mt][r2] *= corr;
                ls[i] *= corr;
            }
            float msc = m[i] * SC;
#pragma unroll
            for (int mt = 0; mt < 4; mt++) {
                float pv[4];
#pragma unroll
                for (int r2 = 0; r2 < 4; r2++)
                    pv[r2] = fast_exp2(__builtin_fmaf(sv[mt][r2], SC, -msc));
                ls[i] += (pv[0] + pv[1]) + (pv[2] + pv[3]);
                uint2 w2;
                w2.x = pack_bf16(pv[0], pv[1]);
                w2.y = pack_bf16(pv[2], pv[3]);
                *(uint2*)&Pw[wv][n * 72 + mt * 16 + quad * 4] = w2;
            }
            __builtin_amdgcn_s_setprio(1);
#pragma unroll
            for (int ks = 0; ks < 2; ks++) {
                bf16x8 pf = *(const bf16x8*)&Pw[wv][n * 72 + ks * 32 + quad * 8];
#pragma unroll
                for (int mt = 0; mt < 4; mt++) {
                    int r = mt * 16 + n;
                    bf16x8 vfr = *(const bf16x8*)&Vs[r * 64 + (((ks * 4 + quad) ^ (n & 7)) * 8)];
                    o[i][mt] = __builtin_amdgcn_mfma_f32_16x16x32_bf16(vfr, pf, o[i][mt], 0, 0, 0);
                }
            }
            __builtin_amdgcn_s_setprio(0);
        }
        __syncthreads();   // publish next buffer (prefetch had full compute to land)
    }

#pragma unroll
    for (int i = 0; i < 2; i++) {
        int qg = q_lo[i] + n;
        // l for q-row n lives split across the 4 lanes of the quad group
        float l = ls[i];
        l += __shfl_xor(l, 16);
        l += __shfl_xor(l, 32);
        float inv = 1.0f / l;
#pragma unroll
        for (int mt = 0; mt < 4; mt++) {
            f32x4 ov;
#pragma unroll
            for (int r2 = 0; r2 < 4; r2++) ov[r2] = o[i][mt][r2] * inv;
            *(f32x4*)(out + (size_t)(b * T + qg) * D + h * HD + mt * 16 + quad * 4) = ov;
        }
    }
}

// ---------------- launch ----------------
extern "C" void kernel_launch(void* const* d_in, const int* in_sizes, int n_in,
                              void* d_out, int out_size, void* d_ws, size_t ws_size,
                              hipStream_t stream) {
    const float* x   = (const float*)d_in[0];
    const float* cs  = (const float*)d_in[1];
    const float* sn  = (const float*)d_in[2];
    const float* wq  = (const float*)d_in[3];
    const float* wk  = (const float*)d_in[4];
    const float* wv  = (const float*)d_in[5];
    const float* wo  = (const float*)d_in[6];
    const float* gq  = (const float*)d_in[7];
    const float* gk  = (const float*)d_in[8];
    const float* gv  = (const float*)d_in[9];
    const float* go  = (const float*)d_in[10];
    float* out = (float*)d_out;

    uint8_t* w = (uint8_t*)d_ws;
    double* wsum  = (double*)w;
    float* xs     = (float*)(w + 256);
    size_t off = 256 + 4 * (size_t)R * 4;
    int8_t* Wq8 = (int8_t*)(w + off); off += (size_t)D * D;
    int8_t* Wk8 = (int8_t*)(w + off); off += (size_t)OKV * D;
    int8_t* Wv8 = (int8_t*)(w + off); off += (size_t)OKV * D;
    int8_t* Wo8 = (int8_t*)(w + off); off += (size_t)D * D;
    int8_t* Xq_q = (int8_t*)(w + off); off += (size_t)R * D;
    int8_t* Xq_k = (int8_t*)(w + off); off += (size_t)R * D;
    int8_t* Xq_v = (int8_t*)(w + off); off += (size_t)R * D;
    float* ab = (float*)(w + off); off += (size_t)R * D * 4;      // attention output (f32)
    float* vb = (float*)(w + off); off += (size_t)R * OKV * 4;    // 8MB region: holds vt (4MB bf16)
    uint16_t* qhb = (uint16_t*)(w + off); off += (size_t)R * D * 2;
    // overlays (regions dead by the time they're written):
    uint16_t* khb = (uint16_t*)Xq_v;   // written by k-gemm AFTER v-gemm consumed Xq_v
    uint16_t* vtb = (uint16_t*)vb;     // v-gemm MODE 2 writes transposed bf16 here directly
    int8_t*   Aq8 = Xq_q;              // written by rmsq AFTER q-gemm consumed Xq_q

    (void)hipMemsetAsync(wsum, 0, 64, stream);

    absmean4_kernel<<<dim3(256, 4), 256, 0, stream>>>(wq, wk, wv, wo, wsum);
    quantw4_kernel<<<dim3(1024, 4), 256, 0, stream>>>(wq, wk, wv, wo, Wq8, Wk8, Wv8, Wo8, wsum);

    rmsq3_kernel<<<R, 256, 0, stream>>>(x, gq, gk, gv, Xq_q, Xq_k, Xq_v,
                                        xs + 0 * R, xs + 1 * R, xs + 2 * R);

    // q (rope fused, bf16), v (transposed bf16, fused vtrans), k (rope fused, over Xq_v)
    gemm_i8_mfma<128, 1><<<dim3(D / 128, R / 128), 256, 0, stream>>>(
        Xq_q, Wq8, qhb, xs + 0 * R, wsum, 0, D * D, D, cs, sn);
    gemm_i8_mfma<64, 2><<<dim3(OKV / 64, R / 128), 256, 0, stream>>>(
        Xq_v, Wv8, vtb, xs + 2 * R, wsum, 2, OKV * D, OKV, cs, sn);
    gemm_i8_mfma<64, 1><<<dim3(OKV / 64, R / 128), 256, 0, stream>>>(
        Xq_k, Wk8, khb, xs + 1 * R, wsum, 1, OKV * D, OKV, cs, sn);

    attn_mfma_kernel<<<dim3(8, H, B), 512, 0, stream>>>(qhb, khb, vtb, ab);

    rmsq_kernel<<<R, 256, 0, stream>>>(ab, go, Aq8, xs + 3 * R);
    gemm_i8_mfma<128, 0><<<dim3(D / 128, R / 128), 256, 0, stream>>>(
        Aq8, Wo8, out, xs + 3 * R, wsum, 3, D * D, D, cs, sn);
}

// Round 6
// 352.224 us; speedup vs baseline: 1.2652x; 1.2652x over previous
//
#include <hip/hip_runtime.h>
#include <stdint.h>

// Problem constants (fixed by setup_inputs)
constexpr int B   = 2;
constexpr int T   = 2048;
constexpr int D   = 2048;
constexpr int H   = 32;
constexpr int KVH = 8;
constexpr int HD  = 64;          // head dim
constexpr int R   = B * T;       // 4096 rows
constexpr int OKV = KVH * HD;    // 512

using bf16x8 = __attribute__((ext_vector_type(8))) __bf16;
using f32x4  = __attribute__((ext_vector_type(4))) float;
using i32x4  = __attribute__((ext_vector_type(4))) int;

__device__ inline float fast_exp2(float x) {
#if __has_builtin(__builtin_amdgcn_exp2f)
    return __builtin_amdgcn_exp2f(x);    // v_exp_f32: computes 2^x
#else
    return exp2f(x);
#endif
}

__device__ inline uint16_t f2bf(float f) {
    uint32_t u = __float_as_uint(f);
    u += 0x7fff + ((u >> 16) & 1);   // RNE
    return (uint16_t)(u >> 16);
}

__device__ inline uint32_t pack_bf16(float a, float b) {
#if __has_builtin(__builtin_amdgcn_cvt_pk_bf16_f32)
    union { __attribute__((ext_vector_type(2))) __bf16 v; uint32_t u; } r;
    r.v = __builtin_amdgcn_cvt_pk_bf16_f32(a, b);
    return r.u;
#else
    return (uint32_t)f2bf(a) | ((uint32_t)f2bf(b) << 16);
#endif
}

// async global->LDS, 16B per lane; LDS dest = (wave-uniform) base + lane*16
__device__ inline void async16(const void* g, void* l) {
    __builtin_amdgcn_global_load_lds((const __attribute__((address_space(1))) unsigned int*)g,
                                     (__attribute__((address_space(3))) unsigned int*)l,
                                     16, 0, 0);
}

// ---------------- weight scales: mean(|w|), all 4 weights in one launch --------
__global__ void absmean4_kernel(const float* __restrict__ w0, const float* __restrict__ w1,
                                const float* __restrict__ w2, const float* __restrict__ w3,
                                double* __restrict__ sums) {
    __shared__ float red[256];
    const float* ws[4] = {w0, w1, w2, w3};
    const int ns[4] = {D * D, OKV * D, OKV * D, D * D};
    int wi = blockIdx.y;
    const float* w = ws[wi];
    int n = ns[wi];
    int tid = threadIdx.x;
    float s = 0.f;
    for (int i = blockIdx.x * 256 + tid; i < n; i += gridDim.x * 256)
        s += fabsf(w[i]);
    red[tid] = s;
    __syncthreads();
    for (int st = 128; st > 0; st >>= 1) {
        if (tid < st) red[tid] += red[tid + st];
        __syncthreads();
    }
    if (tid == 0) atomicAdd(&sums[wi], (double)red[0]);
}

// ---------------- ternary weight quantization, all 4 in one launch ----------------
__global__ void quantw4_kernel(const float* __restrict__ w0, const float* __restrict__ w1,
                               const float* __restrict__ w2, const float* __restrict__ w3,
                               int8_t* __restrict__ o0, int8_t* __restrict__ o1,
                               int8_t* __restrict__ o2, int8_t* __restrict__ o3,
                               const double* __restrict__ sums) {
    const float* ws[4] = {w0, w1, w2, w3};
    int8_t* os[4] = {o0, o1, o2, o3};
    const int ns[4] = {D * D, OKV * D, OKV * D, D * D};
    int wi = blockIdx.y;
    const float* w = ws[wi];
    int8_t* o = os[wi];
    int n = ns[wi];
    float wsc = fmaxf((float)(sums[wi] / (double)n), 1e-5f);
    for (int i = blockIdx.x * 256 + threadIdx.x; i < n; i += gridDim.x * 256) {
        float q = rintf(w[i] / wsc);
        q = fminf(fmaxf(q, -1.f), 1.f);
        o[i] = (int8_t)q;
    }
}

// ---------------- fused rmsnorm + absmax int8 quant for q,k,v ----------------
__global__ __launch_bounds__(256) void rmsq3_kernel(const float* __restrict__ X,
        const float* __restrict__ g0, const float* __restrict__ g1, const float* __restrict__ g2,
        int8_t* __restrict__ o0, int8_t* __restrict__ o1, int8_t* __restrict__ o2,
        float* __restrict__ s0, float* __restrict__ s1, float* __restrict__ s2) {
    __shared__ float red[256];
    int row = blockIdx.x, tid = threadIdx.x;
    const float* xr = X + (size_t)row * D;
    float xv[8];
    float ss = 0.f;
#pragma unroll
    for (int i = 0; i < 8; i++) { xv[i] = xr[tid + 256 * i]; ss += xv[i] * xv[i]; }
    red[tid] = ss;
    __syncthreads();
    for (int st = 128; st > 0; st >>= 1) {
        if (tid < st) red[tid] += red[tid + st];
        __syncthreads();
    }
    float rstd = 1.0f / sqrtf(red[0] / (float)D + 1e-6f);

    const float* gs[3] = {g0, g1, g2};
    int8_t* os[3] = {o0, o1, o2};
    float* sc[3] = {s0, s1, s2};
#pragma unroll
    for (int v = 0; v < 3; v++) {
        float xn[8];
        float amax = 0.f;
#pragma unroll
        for (int i = 0; i < 8; i++) {
            xn[i] = xv[i] * rstd * gs[v][tid + 256 * i];
            amax = fmaxf(amax, fabsf(xn[i]));
        }
        __syncthreads();
        red[tid] = amax;
        __syncthreads();
        for (int st = 128; st > 0; st >>= 1) {
            if (tid < st) red[tid] = fmaxf(red[tid], red[tid + st]);
            __syncthreads();
        }
        float xsv = fmaxf(red[0], 1e-5f);
        float q127 = 127.0f / xsv;
#pragma unroll
        for (int i = 0; i < 8; i++) {
            float q = rintf(xn[i] * q127);
            q = fminf(fmaxf(q, -128.f), 127.f);
            os[v][(size_t)row * D + tid + 256 * i] = (int8_t)q;
        }
        if (tid == 0) sc[v][row] = xsv;
    }
}

// ---------------- rmsnorm + quant (single, for o-proj input) ----------------
// register-cached: one global read of the row, like rmsq3
__global__ __launch_bounds__(256) void rmsq_kernel(const float* __restrict__ X,
                                                   const float* __restrict__ g,
                                                   int8_t* __restrict__ Xq,
                                                   float* __restrict__ xs_out) {
    __shared__ float red[256];
    int row = blockIdx.x, tid = threadIdx.x;
    const float* xr = X + (size_t)row * D;
    float xv[8];
    float ss = 0.f;
#pragma unroll
    for (int i = 0; i < 8; i++) { xv[i] = xr[tid + 256 * i]; ss += xv[i] * xv[i]; }
    red[tid] = ss;
    __syncthreads();
    for (int st = 128; st > 0; st >>= 1) {
        if (tid < st) red[tid] += red[tid + st];
        __syncthreads();
    }
    float rstd = 1.0f / sqrtf(red[0] / (float)D + 1e-6f);

    float xn[8];
    float amax = 0.f;
#pragma unroll
    for (int i = 0; i < 8; i++) {
        xn[i] = xv[i] * rstd * g[tid + 256 * i];
        amax = fmaxf(amax, fabsf(xn[i]));
    }
    __syncthreads();
    red[tid] = amax;
    __syncthreads();
    for (int st = 128; st > 0; st >>= 1) {
        if (tid < st) red[tid] = fmaxf(red[tid], red[tid + st]);
        __syncthreads();
    }
    float xs = fmaxf(red[0], 1e-5f);
    float q127 = 127.0f / xs;
#pragma unroll
    for (int i = 0; i < 8; i++) {
        float q = rintf(xn[i] * q127);
        q = fminf(fmaxf(q, -128.f), 127.f);
        Xq[(size_t)row * D + tid + 256 * i] = (int8_t)q;
    }
    if (tid == 0) xs_out[row] = xs;
}

// ---------------- i8 MFMA GEMM, wave = 32 rows x BN cols ----------------
// MODE 0: f32 output. MODE 1: bf16 output with fused RoPE (rope partners
// col and col+32 are acc[mt][nt] / acc[mt][nt+2] in the same lane).
// MODE 2: v-proj -> transposed bf16 output vt[(b*KVH+kvh)*64+d][t]
// (fuses the old vtrans kernel: 4 consecutive tokens per lane = 8B store).
template<int BN, int MODE>
__global__ __launch_bounds__(256) void gemm_i8_mfma(const int8_t* __restrict__ Xq,
                                                    const int8_t* __restrict__ W8,
                                                    void* __restrict__ outp,
                                                    const float* __restrict__ xs,
                                                    const double* __restrict__ wsum, int wi,
                                                    int nw, int O,
                                                    const float* __restrict__ cs,
                                                    const float* __restrict__ sn) {
    constexpr int NT = BN / 16;          // n-tiles per wave (full BN span)
    __shared__ __align__(16) uint8_t As[128 * 128];
    __shared__ __align__(16) uint8_t Bs[BN * 128];

    const int tid  = threadIdx.x;
    const int lane = tid & 63;
    const int wv   = tid >> 6;
    const int n    = lane & 15, quad = lane >> 4;
    const int row0 = blockIdx.y * 128;
    const int col0 = blockIdx.x * BN;

    i32x4 acc[2][NT] = {};

    for (int k0 = 0; k0 < D; k0 += 128) {
        __syncthreads();
#pragma unroll
        for (int j = 0; j < 4; j++) {
            int p = wv * 256 + j * 64 + lane;
            int r = p >> 3, s = p & 7;
            int c = s ^ (r & 7);
            async16(Xq + (size_t)(row0 + r) * D + k0 + c * 16,
                    &As[(size_t)(wv * 256 + j * 64) * 16]);
        }
#pragma unroll
        for (int j = 0; j < BN / 32; j++) {
            int p = wv * (BN * 2) + j * 64 + lane;
            int r = p >> 3, s = p & 7;
            int c = s ^ (r & 7);
            async16(W8 + (size_t)(col0 + r) * D + k0 + c * 16,
                    &Bs[(size_t)(wv * (BN * 2) + j * 64) * 16]);
        }
        __syncthreads();
#pragma unroll
        for (int t = 0; t < 2; t++) {
            i32x4 af[2], bfr[NT];
#pragma unroll
            for (int mt = 0; mt < 2; mt++) {
                int r = wv * 32 + mt * 16 + n;
                af[mt] = *(const i32x4*)&As[r * 128 + (((t * 4 + quad) ^ (r & 7)) * 16)];
            }
#pragma unroll
            for (int nt = 0; nt < NT; nt++) {
                int r = nt * 16 + n;
                bfr[nt] = *(const i32x4*)&Bs[r * 128 + (((t * 4 + quad) ^ (r & 7)) * 16)];
            }
#pragma unroll
            for (int mt = 0; mt < 2; mt++)
#pragma unroll
                for (int nt = 0; nt < NT; nt++)
                    acc[mt][nt] = __builtin_amdgcn_mfma_i32_16x16x64_i8(af[mt], bfr[nt], acc[mt][nt], 0, 0, 0);
        }
    }
    float w = fmaxf((float)(wsum[wi] / (double)nw), 1e-5f);
#pragma unroll
    for (int mt = 0; mt < 2; mt++) {
        if (MODE == 2) {
            // transposed bf16 write: rows are 4 consecutive tokens per lane
            int rowb = row0 + wv * 32 + mt * 16 + quad * 4;
            int bb = rowb >> 11;              // rowb / T
            int tb = rowb & (T - 1);
            float fr[4];
#pragma unroll
            for (int r2 = 0; r2 < 4; r2++)
                fr[r2] = w * xs[rowb + r2] * (1.0f / 127.0f);
            uint16_t* o16 = (uint16_t*)outp;
#pragma unroll
            for (int nt = 0; nt < NT; nt++) {
                int col = col0 + nt * 16 + n;
                int kvh = col >> 6, d = col & 63;
                uint2 w2;
                w2.x = pack_bf16((float)acc[mt][nt][0] * fr[0], (float)acc[mt][nt][1] * fr[1]);
                w2.y = pack_bf16((float)acc[mt][nt][2] * fr[2], (float)acc[mt][nt][3] * fr[3]);
                *(uint2*)(o16 + ((size_t)(bb * KVH + kvh) * 64 + d) * T + tb) = w2;
            }
            continue;
        }
#pragma unroll
        for (int r2 = 0; r2 < 4; r2++) {
            int row = row0 + wv * 32 + mt * 16 + quad * 4 + r2;
            float f = w * xs[row] * (1.0f / 127.0f);
            if (MODE == 0) {
                float* out = (float*)outp;
#pragma unroll
                for (int nt = 0; nt < NT; nt++)
                    out[(size_t)row * O + col0 + nt * 16 + n] = (float)acc[mt][nt][r2] * f;
            } else {
                uint16_t* out = (uint16_t*)outp;
                int t = row & (T - 1);
#pragma unroll
                for (int nt = 0; nt < NT; nt++) {
                    if ((nt & 3) >= 2) continue;   // rope pair handled at nt, nt+2
                    int i = (nt * 16 + n) & 63;
                    float a  = (float)acc[mt][nt][r2] * f;
                    float bb = (float)acc[mt][nt + 2][r2] * f;
                    float c0 = cs[t * HD + i],      s0 = sn[t * HD + i];
                    float c1 = cs[t * HD + i + 32], s1 = sn[t * HD + i + 32];
                    out[(size_t)row * O + col0 + nt * 16 + n]       = f2bf(a * c0 - bb * s0);
                    out[(size_t)row * O + col0 + (nt + 2) * 16 + n] = f2bf(bb * c1 + a * s1);
                }
            }
        }
    }
}

// ---------------- MFMA flash attention: 8-wave blocks, 2 blocks/CU ----
// grid (8, H, B) = 512 blocks (grid-limited to 2/CU), 512 threads (8 waves).
// Block p handles causal strips p and 15-p; wave wv owns 2 q-tiles:
// {p,15-p}*128 + wv*16. The pairing gives every block exactly
// (2p+2)+(32-2p) = 34 tile-activations over 32-2p staged chunks: balanced
// blocks, 2 tile-computes per staged chunk.
// __launch_bounds__(512, 4): VGPR cap 128. DO NOT raise the min-waves arg --
// (512,6) caps VGPR at ~85 and this structure needs ~90: it spills to scratch
// (r5: FETCH+WRITE 440MB, 173us vs 91us). Grid is 2 blocks/CU anyway, so a
// tighter bound cannot buy occupancy, only spill.
// Register diet keeps VGPR ~60 (no kf/vf arrays, scalar l accumulation).
// Defer-max (T13, THR=8 log2-units) + s_setprio around MFMA clusters (T5).
__global__ __launch_bounds__(512, 4) void attn_mfma_kernel(const uint16_t* __restrict__ qh,
                                                           const uint16_t* __restrict__ kh,
                                                           const uint16_t* __restrict__ vt,
                                                           float* __restrict__ out) {
    __shared__ __align__(16) uint16_t KsB[2][64 * 64];
    __shared__ __align__(16) uint16_t VtB[2][64 * 64];
    __shared__ __align__(16) uint16_t Pw[8][16 * 72];   // per-wave P [q][key] (one tile)

    const int tid  = threadIdx.x;
    const int lane = tid & 63;
    const int wv   = tid >> 6;            // 0..7
    const int p = blockIdx.x, h = blockIdx.y, b = blockIdx.z;
    const int kvh = h >> 2;               // n_rep = 4
    const int n = lane & 15, quad = lane >> 4;
    const float SC = 0.125f * 1.44269504089f;   // score -> log2 units
    const float DEFER = 44.3614f;               // 8 / SC: defer-max threshold (score units)

    // 2 q-tiles per wave: one from strip p (short), one from strip 15-p (long)
    int q_lo[2] = { p * 128 + wv * 16, (15 - p) * 128 + wv * 16 };

    bf16x8 qf[2][2];
#pragma unroll
    for (int i = 0; i < 2; i++) {
        const uint16_t* qp = qh + (size_t)(b * T + q_lo[i] + n) * D + h * HD + quad * 8;
        qf[i][0] = *(const bf16x8*)(qp);
        qf[i][1] = *(const bf16x8*)(qp + 32);
    }

    f32x4 o[2][4] = {};
    float ls[2] = { 0.f, 0.f };
    float m[2] = { -INFINITY, -INFINITY };

    const uint16_t* kbase = kh + (size_t)b * T * OKV + kvh * HD;
    const uint16_t* vbase = vt + (size_t)(b * KVH + kvh) * 64 * T;

    const int nch = 32 - 2 * p;           // chunks for the longer strip (15-p)

    // stage chunk 0 -> buf 0: 512 threads x 16B = exactly one 64x64 bf16 tile each
    {
        int r = tid >> 3, sl = tid & 7;
        int c = sl ^ (r & 7);
        async16(kbase + (size_t)r * OKV + c * 8, &KsB[0][wv * 512]);
        async16(vbase + (size_t)r * T + c * 8,   &VtB[0][wv * 512]);
    }
    __syncthreads();

    for (int ch = 0; ch < nch; ch++) {
        const int cur = ch & 1;
        if (ch + 1 < nch) {   // prefetch next chunk into alternate buffer
            const int t1 = (ch + 1) * 64;
            int r = tid >> 3, sl = tid & 7;
            int c = sl ^ (r & 7);
            async16(kbase + (size_t)(t1 + r) * OKV + c * 8, &KsB[cur ^ 1][wv * 512]);
            async16(vbase + (size_t)r * T + t1 + c * 8,     &VtB[cur ^ 1][wv * 512]);
        }
        const int t0 = ch * 64;
        const uint16_t* Ks = KsB[cur];
        const uint16_t* Vs = VtB[cur];

        // fused per-tile: QK^T -> softmax -> P roundtrip -> PV^T
#pragma unroll
        for (int i = 0; i < 2; i++) {
            if (t0 > q_lo[i] + 15) continue;
            f32x4 sv[4] = {};
            __builtin_amdgcn_s_setprio(1);
#pragma unroll
            for (int ks = 0; ks < 2; ks++)
#pragma unroll
                for (int mt = 0; mt < 4; mt++) {
                    int r = mt * 16 + n;
                    bf16x8 kfr = *(const bf16x8*)&Ks[r * 64 + (((ks * 4 + quad) ^ (n & 7)) * 8)];
                    sv[mt] = __builtin_amdgcn_mfma_f32_16x16x32_bf16(kfr, qf[i][ks], sv[mt], 0, 0, 0);
                }
            __builtin_amdgcn_s_setprio(0);

            const int qg = q_lo[i] + n;
            const bool diag = (t0 + 63 > q_lo[i]);
            float mloc = -INFINITY;
#pragma unroll
            for (int mt = 0; mt < 4; mt++)
#pragma unroll
                for (int r2 = 0; r2 < 4; r2++) {
                    float x = sv[mt][r2];
                    if (diag) {
                        int kg = t0 + mt * 16 + quad * 4 + r2;
                        x = (kg > qg) ? -INFINITY : x;
                        sv[mt][r2] = x;
                    }
                    mloc = fmaxf(mloc, x);
                }
            mloc = fmaxf(mloc, __shfl_xor(mloc, 16));
            mloc = fmaxf(mloc, __shfl_xor(mloc, 32));
            // defer-max: only pay the rescale pass when the max moved >DEFER.
            // P values then bounded by 2^8; f32 accumulation has ample headroom.
            bool upd = (mloc > m[i] + DEFER);
            if (__ballot(upd)) {
                float mnew = fmaxf(m[i], mloc);
                float corr = fast_exp2((m[i] - mnew) * SC);   // ==1 when unchanged; 0 on first chunk
                m[i] = mnew;
#pragma unroll
                for (int mt = 0; mt < 4; mt++)
#pragma unroll
                    for (int r2 = 0; r2 < 4; r2++) o[i][mt][r2] *= corr;
                ls[i] *= corr;
            }
            float msc = m[i] * SC;
#pragma unroll
            for (int mt = 0; mt < 4; mt++) {
                float pv[4];
#pragma unroll
                for (int r2 = 0; r2 < 4; r2++)
                    pv[r2] = fast_exp2(__builtin_fmaf(sv[mt][r2], SC, -msc));
                ls[i] += (pv[0] + pv[1]) + (pv[2] + pv[3]);
                uint2 w2;
                w2.x = pack_bf16(pv[0], pv[1]);
                w2.y = pack_bf16(pv[2], pv[3]);
                *(uint2*)&Pw[wv][n * 72 + mt * 16 + quad * 4] = w2;
            }
            __builtin_amdgcn_s_setprio(1);
#pragma unroll
            for (int ks = 0; ks < 2; ks++) {
                bf16x8 pf = *(const bf16x8*)&Pw[wv][n * 72 + ks * 32 + quad * 8];
#pragma unroll
                for (int mt = 0; mt < 4; mt++) {
                    int r = mt * 16 + n;
                    bf16x8 vfr = *(const bf16x8*)&Vs[r * 64 + (((ks * 4 + quad) ^ (n & 7)) * 8)];
                    o[i][mt] = __builtin_amdgcn_mfma_f32_16x16x32_bf16(vfr, pf, o[i][mt], 0, 0, 0);
                }
            }
            __builtin_amdgcn_s_setprio(0);
        }
        __syncthreads();   // publish next buffer (prefetch had full compute to land)
    }

#pragma unroll
    for (int i = 0; i < 2; i++) {
        int qg = q_lo[i] + n;
        // l for q-row n lives split across the 4 lanes of the quad group
        float l = ls[i];
        l += __shfl_xor(l, 16);
        l += __shfl_xor(l, 32);
        float inv = 1.0f / l;
#pragma unroll
        for (int mt = 0; mt < 4; mt++) {
            f32x4 ov;
#pragma unroll
            for (int r2 = 0; r2 < 4; r2++) ov[r2] = o[i][mt][r2] * inv;
            *(f32x4*)(out + (size_t)(b * T + qg) * D + h * HD + mt * 16 + quad * 4) = ov;
        }
    }
}

// ---------------- launch ----------------
extern "C" void kernel_launch(void* const* d_in, const int* in_sizes, int n_in,
                              void* d_out, int out_size, void* d_ws, size_t ws_size,
                              hipStream_t stream) {
    const float* x   = (const float*)d_in[0];
    const float* cs  = (const float*)d_in[1];
    const float* sn  = (const float*)d_in[2];
    const float* wq  = (const float*)d_in[3];
    const float* wk  = (const float*)d_in[4];
    const float* wv  = (const float*)d_in[5];
    const float* wo  = (const float*)d_in[6];
    const float* gq  = (const float*)d_in[7];
    const float* gk  = (const float*)d_in[8];
    const float* gv  = (const float*)d_in[9];
    const float* go  = (const float*)d_in[10];
    float* out = (float*)d_out;

    uint8_t* w = (uint8_t*)d_ws;
    double* wsum  = (double*)w;
    float* xs     = (float*)(w + 256);
    size_t off = 256 + 4 * (size_t)R * 4;
    int8_t* Wq8 = (int8_t*)(w + off); off += (size_t)D * D;
    int8_t* Wk8 = (int8_t*)(w + off); off += (size_t)OKV * D;
    int8_t* Wv8 = (int8_t*)(w + off); off += (size_t)OKV * D;
    int8_t* Wo8 = (int8_t*)(w + off); off += (size_t)D * D;
    int8_t* Xq_q = (int8_t*)(w + off); off += (size_t)R * D;
    int8_t* Xq_k = (int8_t*)(w + off); off += (size_t)R * D;
    int8_t* Xq_v = (int8_t*)(w + off); off += (size_t)R * D;
    float* ab = (float*)(w + off); off += (size_t)R * D * 4;      // attention output (f32)
    float* vb = (float*)(w + off); off += (size_t)R * OKV * 4;    // 8MB region: holds vt (4MB bf16)
    uint16_t* qhb = (uint16_t*)(w + off); off += (size_t)R * D * 2;
    // overlays (regions dead by the time they're written):
    uint16_t* khb = (uint16_t*)Xq_v;   // written by k-gemm AFTER v-gemm consumed Xq_v
    uint16_t* vtb = (uint16_t*)vb;     // v-gemm MODE 2 writes transposed bf16 here directly
    int8_t*   Aq8 = Xq_q;              // written by rmsq AFTER q-gemm consumed Xq_q

    (void)hipMemsetAsync(wsum, 0, 64, stream);

    absmean4_kernel<<<dim3(256, 4), 256, 0, stream>>>(wq, wk, wv, wo, wsum);
    quantw4_kernel<<<dim3(1024, 4), 256, 0, stream>>>(wq, wk, wv, wo, Wq8, Wk8, Wv8, Wo8, wsum);

    rmsq3_kernel<<<R, 256, 0, stream>>>(x, gq, gk, gv, Xq_q, Xq_k, Xq_v,
                                        xs + 0 * R, xs + 1 * R, xs + 2 * R);

    // q (rope fused, bf16), v (transposed bf16, fused vtrans), k (rope fused, over Xq_v)
    gemm_i8_mfma<128, 1><<<dim3(D / 128, R / 128), 256, 0, stream>>>(
        Xq_q, Wq8, qhb, xs + 0 * R, wsum, 0, D * D, D, cs, sn);
    gemm_i8_mfma<64, 2><<<dim3(OKV / 64, R / 128), 256, 0, stream>>>(
        Xq_v, Wv8, vtb, xs + 2 * R, wsum, 2, OKV * D, OKV, cs, sn);
    gemm_i8_mfma<64, 1><<<dim3(OKV / 64, R / 128), 256, 0, stream>>>(
        Xq_k, Wk8, khb, xs + 1 * R, wsum, 1, OKV * D, OKV, cs, sn);

    attn_mfma_kernel<<<dim3(8, H, B), 512, 0, stream>>>(qhb, khb, vtb, ab);

    rmsq_kernel<<<R, 256, 0, stream>>>(ab, go, Aq8, xs + 3 * R);
    gemm_i8_mfma<128, 0><<<dim3(D / 128, R / 128), 256, 0, stream>>>(
        Aq8, Wo8, out, xs + 3 * R, wsum, 3, D * D, D, cs, sn);
}

// Round 8
// 331.788 us; speedup vs baseline: 1.3431x; 1.0616x over previous
//
#include <hip/hip_runtime.h>
#include <stdint.h>

// Problem constants (fixed by setup_inputs)
constexpr int B   = 2;
constexpr int T   = 2048;
constexpr int D   = 2048;
constexpr int H   = 32;
constexpr int KVH = 8;
constexpr int HD  = 64;          // head dim
constexpr int R   = B * T;       // 4096 rows
constexpr int OKV = KVH * HD;    // 512

using bf16x8 = __attribute__((ext_vector_type(8))) __bf16;
using f32x4  = __attribute__((ext_vector_type(4))) float;
using i32x4  = __attribute__((ext_vector_type(4))) int;

__device__ inline float fast_exp2(float x) {
#if __has_builtin(__builtin_amdgcn_exp2f)
    return __builtin_amdgcn_exp2f(x);    // v_exp_f32: computes 2^x
#else
    return exp2f(x);
#endif
}

__device__ inline float max3f(float a, float b, float c) {
    return fmaxf(fmaxf(a, b), c);        // clang fuses to v_max3_f32 on gfx9+
}

__device__ inline uint16_t f2bf(float f) {
    uint32_t u = __float_as_uint(f);
    u += 0x7fff + ((u >> 16) & 1);   // RNE
    return (uint16_t)(u >> 16);
}

__device__ inline uint32_t pack_bf16(float a, float b) {
#if __has_builtin(__builtin_amdgcn_cvt_pk_bf16_f32)
    union { __attribute__((ext_vector_type(2))) __bf16 v; uint32_t u; } r;
    r.v = __builtin_amdgcn_cvt_pk_bf16_f32(a, b);
    return r.u;
#else
    return (uint32_t)f2bf(a) | ((uint32_t)f2bf(b) << 16);
#endif
}

// async global->LDS, 16B per lane; LDS dest = (wave-uniform) base + lane*16
__device__ inline void async16(const void* g, void* l) {
    __builtin_amdgcn_global_load_lds((const __attribute__((address_space(1))) unsigned int*)g,
                                     (__attribute__((address_space(3))) unsigned int*)l,
                                     16, 0, 0);
}

// ---------------- weight scales: mean(|w|), all 4 weights in one launch --------
__global__ void absmean4_kernel(const float* __restrict__ w0, const float* __restrict__ w1,
                                const float* __restrict__ w2, const float* __restrict__ w3,
                                double* __restrict__ sums) {
    __shared__ float red[256];
    const float* ws[4] = {w0, w1, w2, w3};
    const int ns[4] = {D * D, OKV * D, OKV * D, D * D};
    int wi = blockIdx.y;
    const float* w = ws[wi];
    int n = ns[wi];
    int tid = threadIdx.x;
    float s = 0.f;
    for (int i = blockIdx.x * 256 + tid; i < n; i += gridDim.x * 256)
        s += fabsf(w[i]);
    red[tid] = s;
    __syncthreads();
    for (int st = 128; st > 0; st >>= 1) {
        if (tid < st) red[tid] += red[tid + st];
        __syncthreads();
    }
    if (tid == 0) atomicAdd(&sums[wi], (double)red[0]);
}

// ---------------- ternary weight quantization, all 4 in one launch ----------------
__global__ void quantw4_kernel(const float* __restrict__ w0, const float* __restrict__ w1,
                               const float* __restrict__ w2, const float* __restrict__ w3,
                               int8_t* __restrict__ o0, int8_t* __restrict__ o1,
                               int8_t* __restrict__ o2, int8_t* __restrict__ o3,
                               const double* __restrict__ sums) {
    const float* ws[4] = {w0, w1, w2, w3};
    int8_t* os[4] = {o0, o1, o2, o3};
    const int ns[4] = {D * D, OKV * D, OKV * D, D * D};
    int wi = blockIdx.y;
    const float* w = ws[wi];
    int8_t* o = os[wi];
    int n = ns[wi];
    float wsc = fmaxf((float)(sums[wi] / (double)n), 1e-5f);
    for (int i = blockIdx.x * 256 + threadIdx.x; i < n; i += gridDim.x * 256) {
        float q = rintf(w[i] / wsc);
        q = fminf(fmaxf(q, -1.f), 1.f);
        o[i] = (int8_t)q;
    }
}

// ---------------- fused rmsnorm + absmax int8 quant for q,k,v ----------------
__global__ __launch_bounds__(256) void rmsq3_kernel(const float* __restrict__ X,
        const float* __restrict__ g0, const float* __restrict__ g1, const float* __restrict__ g2,
        int8_t* __restrict__ o0, int8_t* __restrict__ o1, int8_t* __restrict__ o2,
        float* __restrict__ s0, float* __restrict__ s1, float* __restrict__ s2) {
    __shared__ float red[256];
    int row = blockIdx.x, tid = threadIdx.x;
    const float* xr = X + (size_t)row * D;
    float xv[8];
    float ss = 0.f;
#pragma unroll
    for (int i = 0; i < 8; i++) { xv[i] = xr[tid + 256 * i]; ss += xv[i] * xv[i]; }
    red[tid] = ss;
    __syncthreads();
    for (int st = 128; st > 0; st >>= 1) {
        if (tid < st) red[tid] += red[tid + st];
        __syncthreads();
    }
    float rstd = 1.0f / sqrtf(red[0] / (float)D + 1e-6f);

    const float* gs[3] = {g0, g1, g2};
    int8_t* os[3] = {o0, o1, o2};
    float* sc[3] = {s0, s1, s2};
#pragma unroll
    for (int v = 0; v < 3; v++) {
        float xn[8];
        float amax = 0.f;
#pragma unroll
        for (int i = 0; i < 8; i++) {
            xn[i] = xv[i] * rstd * gs[v][tid + 256 * i];
            amax = fmaxf(amax, fabsf(xn[i]));
        }
        __syncthreads();
        red[tid] = amax;
        __syncthreads();
        for (int st = 128; st > 0; st >>= 1) {
            if (tid < st) red[tid] = fmaxf(red[tid], red[tid + st]);
            __syncthreads();
        }
        float xsv = fmaxf(red[0], 1e-5f);
        float q127 = 127.0f / xsv;
#pragma unroll
        for (int i = 0; i < 8; i++) {
            float q = rintf(xn[i] * q127);
            q = fminf(fmaxf(q, -128.f), 127.f);
            os[v][(size_t)row * D + tid + 256 * i] = (int8_t)q;
        }
        if (tid == 0) sc[v][row] = xsv;
    }
}

// ---------------- rmsnorm + quant (single, for o-proj input) ----------------
// register-cached: one global read of the row, like rmsq3
__global__ __launch_bounds__(256) void rmsq_kernel(const float* __restrict__ X,
                                                   const float* __restrict__ g,
                                                   int8_t* __restrict__ Xq,
                                                   float* __restrict__ xs_out) {
    __shared__ float red[256];
    int row = blockIdx.x, tid = threadIdx.x;
    const float* xr = X + (size_t)row * D;
    float xv[8];
    float ss = 0.f;
#pragma unroll
    for (int i = 0; i < 8; i++) { xv[i] = xr[tid + 256 * i]; ss += xv[i] * xv[i]; }
    red[tid] = ss;
    __syncthreads();
    for (int st = 128; st > 0; st >>= 1) {
        if (tid < st) red[tid] += red[tid + st];
        __syncthreads();
    }
    float rstd = 1.0f / sqrtf(red[0] / (float)D + 1e-6f);

    float xn[8];
    float amax = 0.f;
#pragma unroll
    for (int i = 0; i < 8; i++) {
        xn[i] = xv[i] * rstd * g[tid + 256 * i];
        amax = fmaxf(amax, fabsf(xn[i]));
    }
    __syncthreads();
    red[tid] = amax;
    __syncthreads();
    for (int st = 128; st > 0; st >>= 1) {
        if (tid < st) red[tid] = fmaxf(red[tid], red[tid + st]);
        __syncthreads();
    }
    float xs = fmaxf(red[0], 1e-5f);
    float q127 = 127.0f / xs;
#pragma unroll
    for (int i = 0; i < 8; i++) {
        float q = rintf(xn[i] * q127);
        q = fminf(fmaxf(q, -128.f), 127.f);
        Xq[(size_t)row * D + tid + 256 * i] = (int8_t)q;
    }
    if (tid == 0) xs_out[row] = xs;
}

// ---------------- i8 MFMA GEMM, wave = 32 rows x BN cols ----------------
// MODE 0: f32 output. MODE 1: bf16 output with fused RoPE (rope partners
// col and col+32 are acc[mt][nt] / acc[mt][nt+2] in the same lane).
template<int BN, int MODE>
__global__ __launch_bounds__(256) void gemm_i8_mfma(const int8_t* __restrict__ Xq,
                                                    const int8_t* __restrict__ W8,
                                                    void* __restrict__ outp,
                                                    const float* __restrict__ xs,
                                                    const double* __restrict__ wsum, int wi,
                                                    int nw, int O,
                                                    const float* __restrict__ cs,
                                                    const float* __restrict__ sn) {
    constexpr int NT = BN / 16;          // n-tiles per wave (full BN span)
    __shared__ __align__(16) uint8_t As[128 * 128];
    __shared__ __align__(16) uint8_t Bs[BN * 128];

    const int tid  = threadIdx.x;
    const int lane = tid & 63;
    const int wv   = tid >> 6;
    const int n    = lane & 15, quad = lane >> 4;
    const int row0 = blockIdx.y * 128;
    const int col0 = blockIdx.x * BN;

    i32x4 acc[2][NT] = {};

    for (int k0 = 0; k0 < D; k0 += 128) {
        __syncthreads();
#pragma unroll
        for (int j = 0; j < 4; j++) {
            int p = wv * 256 + j * 64 + lane;
            int r = p >> 3, s = p & 7;
            int c = s ^ (r & 7);
            async16(Xq + (size_t)(row0 + r) * D + k0 + c * 16,
                    &As[(size_t)(wv * 256 + j * 64) * 16]);
        }
#pragma unroll
        for (int j = 0; j < BN / 32; j++) {
            int p = wv * (BN * 2) + j * 64 + lane;
            int r = p >> 3, s = p & 7;
            int c = s ^ (r & 7);
            async16(W8 + (size_t)(col0 + r) * D + k0 + c * 16,
                    &Bs[(size_t)(wv * (BN * 2) + j * 64) * 16]);
        }
        __syncthreads();
#pragma unroll
        for (int t = 0; t < 2; t++) {
            i32x4 af[2], bfr[NT];
#pragma unroll
            for (int mt = 0; mt < 2; mt++) {
                int r = wv * 32 + mt * 16 + n;
                af[mt] = *(const i32x4*)&As[r * 128 + (((t * 4 + quad) ^ (r & 7)) * 16)];
            }
#pragma unroll
            for (int nt = 0; nt < NT; nt++) {
                int r = nt * 16 + n;
                bfr[nt] = *(const i32x4*)&Bs[r * 128 + (((t * 4 + quad) ^ (r & 7)) * 16)];
            }
#pragma unroll
            for (int mt = 0; mt < 2; mt++)
#pragma unroll
                for (int nt = 0; nt < NT; nt++)
                    acc[mt][nt] = __builtin_amdgcn_mfma_i32_16x16x64_i8(af[mt], bfr[nt], acc[mt][nt], 0, 0, 0);
        }
    }
    float w = fmaxf((float)(wsum[wi] / (double)nw), 1e-5f);
#pragma unroll
    for (int mt = 0; mt < 2; mt++) {
#pragma unroll
        for (int r2 = 0; r2 < 4; r2++) {
            int row = row0 + wv * 32 + mt * 16 + quad * 4 + r2;
            float f = w * xs[row] * (1.0f / 127.0f);
            if (MODE == 0) {
                float* out = (float*)outp;
#pragma unroll
                for (int nt = 0; nt < NT; nt++)
                    out[(size_t)row * O + col0 + nt * 16 + n] = (float)acc[mt][nt][r2] * f;
            } else {
                uint16_t* out = (uint16_t*)outp;
                int t = row & (T - 1);
#pragma unroll
                for (int nt = 0; nt < NT; nt++) {
                    if ((nt & 3) >= 2) continue;   // rope pair handled at nt, nt+2
                    int i = (nt * 16 + n) & 63;
                    float a  = (float)acc[mt][nt][r2] * f;
                    float bb = (float)acc[mt][nt + 2][r2] * f;
                    float c0 = cs[t * HD + i],      s0 = sn[t * HD + i];
                    float c1 = cs[t * HD + i + 32], s1 = sn[t * HD + i + 32];
                    out[(size_t)row * O + col0 + nt * 16 + n]       = f2bf(a * c0 - bb * s0);
                    out[(size_t)row * O + col0 + (nt + 2) * 16 + n] = f2bf(bb * c1 + a * s1);
                }
            }
        }
    }
}

// ---------------- merged k+v projection GEMM ----------------
// blockIdx.z: 0 = v-proj (transposed bf16 epilogue), 1 = k-proj (RoPE bf16).
// Standalone k/v launches were 256 blocks = 1 block/CU = 1 wave/SIMD -- zero
// latency hiding. Merged: 512 blocks = 2 blocks/CU = 8 waves/CU, and one
// launch gap removed. NOTE: k output must NOT alias Xq_v here (v blocks read
// Xq_v concurrently) -- kout lives in the upper half of the old vb region.
__global__ __launch_bounds__(256) void gemm_kv_mfma(const int8_t* __restrict__ Xv,
                                                    const int8_t* __restrict__ Xk,
                                                    const int8_t* __restrict__ Wv8,
                                                    const int8_t* __restrict__ Wk8,
                                                    uint16_t* __restrict__ vt,
                                                    uint16_t* __restrict__ kout,
                                                    const float* __restrict__ xsv,
                                                    const float* __restrict__ xsk,
                                                    const double* __restrict__ wsum,
                                                    const float* __restrict__ cs,
                                                    const float* __restrict__ sn) {
    constexpr int BN = 64, NT = 4;
    __shared__ __align__(16) uint8_t As[128 * 128];
    __shared__ __align__(16) uint8_t Bs[BN * 128];

    const int z = blockIdx.z;            // 0 = v, 1 = k
    const int8_t* Xq = z ? Xk : Xv;
    const int8_t* W8 = z ? Wk8 : Wv8;
    const float* xs  = z ? xsk : xsv;

    const int tid  = threadIdx.x;
    const int lane = tid & 63;
    const int wv   = tid >> 6;
    const int n    = lane & 15, quad = lane >> 4;
    const int row0 = blockIdx.y * 128;
    const int col0 = blockIdx.x * BN;

    i32x4 acc[2][NT] = {};

    for (int k0 = 0; k0 < D; k0 += 128) {
        __syncthreads();
#pragma unroll
        for (int j = 0; j < 4; j++) {
            int p = wv * 256 + j * 64 + lane;
            int r = p >> 3, s = p & 7;
            int c = s ^ (r & 7);
            async16(Xq + (size_t)(row0 + r) * D + k0 + c * 16,
                    &As[(size_t)(wv * 256 + j * 64) * 16]);
        }
#pragma unroll
        for (int j = 0; j < BN / 32; j++) {
            int p = wv * (BN * 2) + j * 64 + lane;
            int r = p >> 3, s = p & 7;
            int c = s ^ (r & 7);
            async16(W8 + (size_t)(col0 + r) * D + k0 + c * 16,
                    &Bs[(size_t)(wv * (BN * 2) + j * 64) * 16]);
        }
        __syncthreads();
#pragma unroll
        for (int t = 0; t < 2; t++) {
            i32x4 af[2], bfr[NT];
#pragma unroll
            for (int mt = 0; mt < 2; mt++) {
                int r = wv * 32 + mt * 16 + n;
                af[mt] = *(const i32x4*)&As[r * 128 + (((t * 4 + quad) ^ (r & 7)) * 16)];
            }
#pragma unroll
            for (int nt = 0; nt < NT; nt++) {
                int r = nt * 16 + n;
                bfr[nt] = *(const i32x4*)&Bs[r * 128 + (((t * 4 + quad) ^ (r & 7)) * 16)];
            }
#pragma unroll
            for (int mt = 0; mt < 2; mt++)
#pragma unroll
                for (int nt = 0; nt < NT; nt++)
                    acc[mt][nt] = __builtin_amdgcn_mfma_i32_16x16x64_i8(af[mt], bfr[nt], acc[mt][nt], 0, 0, 0);
        }
    }
    float w = fmaxf((float)(wsum[z ? 1 : 2] / (double)(OKV * D)), 1e-5f);
    if (z == 0) {
        // v: transposed bf16 write vt[(b*KVH+kvh)*64+d][t]
#pragma unroll
        for (int mt = 0; mt < 2; mt++) {
            int rowb = row0 + wv * 32 + mt * 16 + quad * 4;
            int bb = rowb >> 11;              // rowb / T
            int tb = rowb & (T - 1);
            float fr[4];
#pragma unroll
            for (int r2 = 0; r2 < 4; r2++)
                fr[r2] = w * xs[rowb + r2] * (1.0f / 127.0f);
#pragma unroll
            for (int nt = 0; nt < NT; nt++) {
                int col = col0 + nt * 16 + n;
                int kvh = col >> 6, d = col & 63;
                uint2 w2;
                w2.x = pack_bf16((float)acc[mt][nt][0] * fr[0], (float)acc[mt][nt][1] * fr[1]);
                w2.y = pack_bf16((float)acc[mt][nt][2] * fr[2], (float)acc[mt][nt][3] * fr[3]);
                *(uint2*)(vt + ((size_t)(bb * KVH + kvh) * 64 + d) * T + tb) = w2;
            }
        }
    } else {
        // k: RoPE-fused bf16 write, row-major [row][OKV]
#pragma unroll
        for (int mt = 0; mt < 2; mt++) {
#pragma unroll
            for (int r2 = 0; r2 < 4; r2++) {
                int row = row0 + wv * 32 + mt * 16 + quad * 4 + r2;
                float f = w * xs[row] * (1.0f / 127.0f);
                int t = row & (T - 1);
#pragma unroll
                for (int nt = 0; nt < 2; nt++) {   // rope pair (nt, nt+2)
                    int i = (nt * 16 + n) & 63;
                    float a  = (float)acc[mt][nt][r2] * f;
                    float bb = (float)acc[mt][nt + 2][r2] * f;
                    float c0 = cs[t * HD + i],      s0 = sn[t * HD + i];
                    float c1 = cs[t * HD + i + 32], s1 = sn[t * HD + i + 32];
                    kout[(size_t)row * OKV + col0 + nt * 16 + n]       = f2bf(a * c0 - bb * s0);
                    kout[(size_t)row * OKV + col0 + (nt + 2) * 16 + n] = f2bf(bb * c1 + a * s1);
                }
            }
        }
    }
}

// ---------------- MFMA flash attention: 8-wave blocks, 2 blocks/CU ----
// grid (8, H, B) = 512 blocks (grid-limited to 2/CU), 512 threads (8 waves).
// Block p handles causal strips p and 15-p; wave wv owns 2 q-tiles:
// {p,15-p}*128 + wv*16. The pairing gives every block exactly
// (2p+2)+(32-2p) = 34 tile-activations over 32-2p staged chunks: balanced
// blocks, 2 tile-computes per staged chunk.
// __launch_bounds__(512, 4): VGPR cap 128. DO NOT raise the min-waves arg --
// (512,6) caps VGPR at ~85 and this structure needs ~90: it spills to scratch
// (r5: FETCH+WRITE 440MB, 173us vs 91us). Grid is 2 blocks/CU anyway, so a
// tighter bound cannot buy occupancy, only spill.
// Register diet keeps VGPR ~60 (no kf/vf arrays, scalar l accumulation).
// Defer-max (T13, THR=8 log2-units) + s_setprio around MFMA clusters (T5).
__global__ __launch_bounds__(512, 4) void attn_mfma_kernel(const uint16_t* __restrict__ qh,
                                                           const uint16_t* __restrict__ kh,
                                                           const uint16_t* __restrict__ vt,
                                                           float* __restrict__ out) {
    __shared__ __align__(16) uint16_t KsB[2][64 * 64];
    __shared__ __align__(16) uint16_t VtB[2][64 * 64];
    __shared__ __align__(16) uint16_t Pw[8][16 * 72];   // per-wave P [q][key] (one tile)

    const int tid  = threadIdx.x;
    const int lane = tid & 63;
    const int wv   = tid >> 6;            // 0..7
    const int p = blockIdx.x, h = blockIdx.y, b = blockIdx.z;
    const int kvh = h >> 2;               // n_rep = 4
    const int n = lane & 15, quad = lane >> 4;
    const float SC = 0.125f * 1.44269504089f;   // score -> log2 units
    const float DEFER = 44.3614f;               // 8 / SC: defer-max threshold (score units)

    // 2 q-tiles per wave: one from strip p (short), one from strip 15-p (long)
    int q_lo[2] = { p * 128 + wv * 16, (15 - p) * 128 + wv * 16 };

    bf16x8 qf[2][2];
#pragma unroll
    for (int i = 0; i < 2; i++) {
        const uint16_t* qp = qh + (size_t)(b * T + q_lo[i] + n) * D + h * HD + quad * 8;
        qf[i][0] = *(const bf16x8*)(qp);
        qf[i][1] = *(const bf16x8*)(qp + 32);
    }

    f32x4 o[2][4] = {};
    float ls[2] = { 0.f, 0.f };
    float m[2] = { -INFINITY, -INFINITY };

    const uint16_t* kbase = kh + (size_t)b * T * OKV + kvh * HD;
    const uint16_t* vbase = vt + (size_t)(b * KVH + kvh) * 64 * T;

    const int nch = 32 - 2 * p;           // chunks for the longer strip (15-p)

    // stage chunk 0 -> buf 0: 512 threads x 16B = exactly one 64x64 bf16 tile each
    {
        int r = tid >> 3, sl = tid & 7;
        int c = sl ^ (r & 7);
        async16(kbase + (size_t)r * OKV + c * 8, &KsB[0][wv * 512]);
        async16(vbase + (size_t)r * T + c * 8,   &VtB[0][wv * 512]);
    }
    __syncthreads();

    for (int ch = 0; ch < nch; ch++) {
        const int cur = ch & 1;
        if (ch + 1 < nch) {   // prefetch next chunk into alternate buffer
            const int t1 = (ch + 1) * 64;
            int r = tid >> 3, sl = tid & 7;
            int c = sl ^ (r & 7);
            async16(kbase + (size_t)(t1 + r) * OKV + c * 8, &KsB[cur ^ 1][wv * 512]);
            async16(vbase + (size_t)r * T + t1 + c * 8,     &VtB[cur ^ 1][wv * 512]);
        }
        const int t0 = ch * 64;
        const uint16_t* Ks = KsB[cur];
        const uint16_t* Vs = VtB[cur];

        // fused per-tile: QK^T -> softmax -> P roundtrip -> PV^T
#pragma unroll
        for (int i = 0; i < 2; i++) {
            if (t0 > q_lo[i] + 15) continue;
            f32x4 sv[4] = {};
            __builtin_amdgcn_s_setprio(1);
#pragma unroll
            for (int ks = 0; ks < 2; ks++)
#pragma unroll
                for (int mt = 0; mt < 4; mt++) {
                    int r = mt * 16 + n;
                    bf16x8 kfr = *(const bf16x8*)&Ks[r * 64 + (((ks * 4 + quad) ^ (n & 7)) * 8)];
                    sv[mt] = __builtin_amdgcn_mfma_f32_16x16x32_bf16(kfr, qf[i][ks], sv[mt], 0, 0, 0);
                }
            __builtin_amdgcn_s_setprio(0);

            const int qg = q_lo[i] + n;
            const bool diag = (t0 + 63 > q_lo[i]);
            if (diag) {        // wave-uniform branch: mask only on diagonal chunks
#pragma unroll
                for (int mt = 0; mt < 4; mt++)
#pragma unroll
                    for (int r2 = 0; r2 < 4; r2++) {
                        int kg = t0 + mt * 16 + quad * 4 + r2;
                        if (kg > qg) sv[mt][r2] = -INFINITY;
                    }
            }
            // row-max via v_max3 tree (15 fmax -> 7 ops)
            float r0 = max3f(sv[0][0], sv[0][1], sv[0][2]);
            float r1 = max3f(sv[0][3], sv[1][0], sv[1][1]);
            float r2m = max3f(sv[1][2], sv[1][3], sv[2][0]);
            float r3 = max3f(sv[2][1], sv[2][2], sv[2][3]);
            float r4 = max3f(sv[3][0], sv[3][1], sv[3][2]);
            float mloc = fmaxf(max3f(max3f(r0, r1, r2m), r3, r4), sv[3][3]);
            mloc = fmaxf(mloc, __shfl_xor(mloc, 16));
            mloc = fmaxf(mloc, __shfl_xor(mloc, 32));
            // defer-max: only pay the rescale pass when the max moved >DEFER.
            // P values then bounded by 2^8; f32 accumulation has ample headroom.
            bool upd = (mloc > m[i] + DEFER);
            if (__ballot(upd)) {
                float mnew = fmaxf(m[i], mloc);
                float corr = fast_exp2((m[i] - mnew) * SC);   // ==1 when unchanged; 0 on first chunk
                m[i] = mnew;
#pragma unroll
                for (int mt = 0; mt < 4; mt++)
#pragma unroll
                    for (int r2 = 0; r2 < 4; r2++) o[i][mt][r2] *= corr;
                ls[i] *= corr;
            }
            float msc = m[i] * SC;
#pragma unroll
            for (int mt = 0; mt < 4; mt++) {
                float pv[4];
#pragma unroll
                for (int r2 = 0; r2 < 4; r2++)
                    pv[r2] = fast_exp2(__builtin_fmaf(sv[mt][r2], SC, -msc));
                ls[i] += (pv[0] + pv[1]) + (pv[2] + pv[3]);
                uint2 w2;
                w2.x = pack_bf16(pv[0], pv[1]);
                w2.y = pack_bf16(pv[2], pv[3]);
                *(uint2*)&Pw[wv][n * 72 + mt * 16 + quad * 4] = w2;
            }
            __builtin_amdgcn_s_setprio(1);
#pragma unroll
            for (int ks = 0; ks < 2; ks++) {
                bf16x8 pf = *(const bf16x8*)&Pw[wv][n * 72 + ks * 32 + quad * 8];
#pragma unroll
                for (int mt = 0; mt < 4; mt++) {
                    int r = mt * 16 + n;
                    bf16x8 vfr = *(const bf16x8*)&Vs[r * 64 + (((ks * 4 + quad) ^ (n & 7)) * 8)];
                    o[i][mt] = __builtin_amdgcn_mfma_f32_16x16x32_bf16(vfr, pf, o[i][mt], 0, 0, 0);
                }
            }
            __builtin_amdgcn_s_setprio(0);
        }
        __syncthreads();   // publish next buffer (prefetch had full compute to land)
    }

#pragma unroll
    for (int i = 0; i < 2; i++) {
        int qg = q_lo[i] + n;
        // l for q-row n lives split across the 4 lanes of the quad group
        float l = ls[i];
        l += __shfl_xor(l, 16);
        l += __shfl_xor(l, 32);
        float inv = 1.0f / l;
#pragma unroll
        for (int mt = 0; mt < 4; mt++) {
            f32x4 ov;
#pragma unroll
            for (int r2 = 0; r2 < 4; r2++) ov[r2] = o[i][mt][r2] * inv;
            *(f32x4*)(out + (size_t)(b * T + qg) * D + h * HD + mt * 16 + quad * 4) = ov;
        }
    }
}

// ---------------- launch ----------------
extern "C" void kernel_launch(void* const* d_in, const int* in_sizes, int n_in,
                              void* d_out, int out_size, void* d_ws, size_t ws_size,
                              hipStream_t stream) {
    const float* x   = (const float*)d_in[0];
    const float* cs  = (const float*)d_in[1];
    const float* sn  = (const float*)d_in[2];
    const float* wq  = (const float*)d_in[3];
    const float* wk  = (const float*)d_in[4];
    const float* wv  = (const float*)d_in[5];
    const float* wo  = (const float*)d_in[6];
    const float* gq  = (const float*)d_in[7];
    const float* gk  = (const float*)d_in[8];
    const float* gv  = (const float*)d_in[9];
    const float* go  = (const float*)d_in[10];
    float* out = (float*)d_out;

    uint8_t* w = (uint8_t*)d_ws;
    double* wsum  = (double*)w;
    float* xs     = (float*)(w + 256);
    size_t off = 256 + 4 * (size_t)R * 4;
    int8_t* Wq8 = (int8_t*)(w + off); off += (size_t)D * D;
    int8_t* Wk8 = (int8_t*)(w + off); off += (size_t)OKV * D;
    int8_t* Wv8 = (int8_t*)(w + off); off += (size_t)OKV * D;
    int8_t* Wo8 = (int8_t*)(w + off); off += (size_t)D * D;
    int8_t* Xq_q = (int8_t*)(w + off); off += (size_t)R * D;
    int8_t* Xq_k = (int8_t*)(w + off); off += (size_t)R * D;
    int8_t* Xq_v = (int8_t*)(w + off); off += (size_t)R * D;
    float* ab = (float*)(w + off); off += (size_t)R * D * 4;      // attention output (f32)
    float* vb = (float*)(w + off); off += (size_t)R * OKV * 4;    // 8MB: vt (4MB) + khb (4MB)
    uint16_t* qhb = (uint16_t*)(w + off); off += (size_t)R * D * 2;
    // vt and k outputs live in the vb region (both written by the merged kv
    // gemm; must NOT alias Xq_k/Xq_v since those are concurrently read).
    // NOTE uint16 element arithmetic: khb = vtb + R*OKV elements = +4MB bytes.
    // (r6 bug: vb + R*OKV in FLOAT units = +8MB = overlapped qhb -> corruption.)
    uint16_t* vtb = (uint16_t*)vb;                  // [0, 4MB)
    uint16_t* khb = vtb + (size_t)R * OKV;          // [4MB, 8MB)
    int8_t*   Aq8 = Xq_q;              // written by rmsq AFTER q-gemm consumed Xq_q

    (void)hipMemsetAsync(wsum, 0, 64, stream);

    absmean4_kernel<<<dim3(256, 4), 256, 0, stream>>>(wq, wk, wv, wo, wsum);
    quantw4_kernel<<<dim3(1024, 4), 256, 0, stream>>>(wq, wk, wv, wo, Wq8, Wk8, Wv8, Wo8, wsum);

    rmsq3_kernel<<<R, 256, 0, stream>>>(x, gq, gk, gv, Xq_q, Xq_k, Xq_v,
                                        xs + 0 * R, xs + 1 * R, xs + 2 * R);

    // q (rope fused, bf16), then merged k+v (v transposed bf16, k rope bf16)
    gemm_i8_mfma<128, 1><<<dim3(D / 128, R / 128), 256, 0, stream>>>(
        Xq_q, Wq8, qhb, xs + 0 * R, wsum, 0, D * D, D, cs, sn);
    gemm_kv_mfma<<<dim3(OKV / 64, R / 128, 2), 256, 0, stream>>>(
        Xq_v, Xq_k, Wv8, Wk8, vtb, khb, xs + 2 * R, xs + 1 * R, wsum, cs, sn);

    attn_mfma_kernel<<<dim3(8, H, B), 512, 0, stream>>>(qhb, khb, vtb, ab);

    rmsq_kernel<<<R, 256, 0, stream>>>(ab, go, Aq8, xs + 3 * R);
    gemm_i8_mfma<128, 0><<<dim3(D / 128, R / 128), 256, 0, stream>>>(
        Aq8, Wo8, out, xs + 3 * R, wsum, 3, D * D, D, cs, sn);
}

// Round 9
// 326.923 us; speedup vs baseline: 1.3631x; 1.0149x over previous
//
#include <hip/hip_runtime.h>
#include <stdint.h>

// Problem constants (fixed by setup_inputs)
constexpr int B   = 2;
constexpr int T   = 2048;
constexpr int D   = 2048;
constexpr int H   = 32;
constexpr int KVH = 8;
constexpr int HD  = 64;          // head dim
constexpr int R   = B * T;       // 4096 rows
constexpr int OKV = KVH * HD;    // 512

using bf16x8 = __attribute__((ext_vector_type(8))) __bf16;
using f32x4  = __attribute__((ext_vector_type(4))) float;
using i32x4  = __attribute__((ext_vector_type(4))) int;

__device__ inline float fast_exp2(float x) {
#if __has_builtin(__builtin_amdgcn_exp2f)
    return __builtin_amdgcn_exp2f(x);    // v_exp_f32: computes 2^x
#else
    return exp2f(x);
#endif
}

__device__ inline float max3f(float a, float b, float c) {
    return fmaxf(fmaxf(a, b), c);        // clang fuses to v_max3_f32 on gfx9+
}

__device__ inline uint16_t f2bf(float f) {
    uint32_t u = __float_as_uint(f);
    u += 0x7fff + ((u >> 16) & 1);   // RNE
    return (uint16_t)(u >> 16);
}

__device__ inline uint32_t pack_bf16(float a, float b) {
#if __has_builtin(__builtin_amdgcn_cvt_pk_bf16_f32)
    union { __attribute__((ext_vector_type(2))) __bf16 v; uint32_t u; } r;
    r.v = __builtin_amdgcn_cvt_pk_bf16_f32(a, b);
    return r.u;
#else
    return (uint32_t)f2bf(a) | ((uint32_t)f2bf(b) << 16);
#endif
}

// async global->LDS, 16B per lane; LDS dest = (wave-uniform) base + lane*16
__device__ inline void async16(const void* g, void* l) {
    __builtin_amdgcn_global_load_lds((const __attribute__((address_space(1))) unsigned int*)g,
                                     (__attribute__((address_space(3))) unsigned int*)l,
                                     16, 0, 0);
}

// ---------------- weight scales: mean(|w|), all 4 weights in one launch --------
__global__ void absmean4_kernel(const float* __restrict__ w0, const float* __restrict__ w1,
                                const float* __restrict__ w2, const float* __restrict__ w3,
                                double* __restrict__ sums) {
    __shared__ float red[256];
    const float* ws[4] = {w0, w1, w2, w3};
    const int ns[4] = {D * D, OKV * D, OKV * D, D * D};
    int wi = blockIdx.y;
    const float* w = ws[wi];
    int n = ns[wi];
    int tid = threadIdx.x;
    float s = 0.f;
    for (int i = blockIdx.x * 256 + tid; i < n; i += gridDim.x * 256)
        s += fabsf(w[i]);
    red[tid] = s;
    __syncthreads();
    for (int st = 128; st > 0; st >>= 1) {
        if (tid < st) red[tid] += red[tid + st];
        __syncthreads();
    }
    if (tid == 0) atomicAdd(&sums[wi], (double)red[0]);
}

// ---------------- ternary weight quantization, all 4 in one launch ----------------
__global__ void quantw4_kernel(const float* __restrict__ w0, const float* __restrict__ w1,
                               const float* __restrict__ w2, const float* __restrict__ w3,
                               int8_t* __restrict__ o0, int8_t* __restrict__ o1,
                               int8_t* __restrict__ o2, int8_t* __restrict__ o3,
                               const double* __restrict__ sums) {
    const float* ws[4] = {w0, w1, w2, w3};
    int8_t* os[4] = {o0, o1, o2, o3};
    const int ns[4] = {D * D, OKV * D, OKV * D, D * D};
    int wi = blockIdx.y;
    const float* w = ws[wi];
    int8_t* o = os[wi];
    int n = ns[wi];
    float wsc = fmaxf((float)(sums[wi] / (double)n), 1e-5f);
    for (int i = blockIdx.x * 256 + threadIdx.x; i < n; i += gridDim.x * 256) {
        float q = rintf(w[i] / wsc);
        q = fminf(fmaxf(q, -1.f), 1.f);
        o[i] = (int8_t)q;
    }
}

// ---------------- fused rmsnorm + absmax int8 quant for q,k,v ----------------
__global__ __launch_bounds__(256) void rmsq3_kernel(const float* __restrict__ X,
        const float* __restrict__ g0, const float* __restrict__ g1, const float* __restrict__ g2,
        int8_t* __restrict__ o0, int8_t* __restrict__ o1, int8_t* __restrict__ o2,
        float* __restrict__ s0, float* __restrict__ s1, float* __restrict__ s2) {
    __shared__ float red[256];
    int row = blockIdx.x, tid = threadIdx.x;
    const float* xr = X + (size_t)row * D;
    float xv[8];
    float ss = 0.f;
#pragma unroll
    for (int i = 0; i < 8; i++) { xv[i] = xr[tid + 256 * i]; ss += xv[i] * xv[i]; }
    red[tid] = ss;
    __syncthreads();
    for (int st = 128; st > 0; st >>= 1) {
        if (tid < st) red[tid] += red[tid + st];
        __syncthreads();
    }
    float rstd = 1.0f / sqrtf(red[0] / (float)D + 1e-6f);

    const float* gs[3] = {g0, g1, g2};
    int8_t* os[3] = {o0, o1, o2};
    float* sc[3] = {s0, s1, s2};
#pragma unroll
    for (int v = 0; v < 3; v++) {
        float xn[8];
        float amax = 0.f;
#pragma unroll
        for (int i = 0; i < 8; i++) {
            xn[i] = xv[i] * rstd * gs[v][tid + 256 * i];
            amax = fmaxf(amax, fabsf(xn[i]));
        }
        __syncthreads();
        red[tid] = amax;
        __syncthreads();
        for (int st = 128; st > 0; st >>= 1) {
            if (tid < st) red[tid] = fmaxf(red[tid], red[tid + st]);
            __syncthreads();
        }
        float xsv = fmaxf(red[0], 1e-5f);
        float q127 = 127.0f / xsv;
#pragma unroll
        for (int i = 0; i < 8; i++) {
            float q = rintf(xn[i] * q127);
            q = fminf(fmaxf(q, -128.f), 127.f);
            os[v][(size_t)row * D + tid + 256 * i] = (int8_t)q;
        }
        if (tid == 0) sc[v][row] = xsv;
    }
}

// ---------------- rmsnorm + quant (single, for o-proj input) ----------------
// register-cached: one global read of the row, like rmsq3
__global__ __launch_bounds__(256) void rmsq_kernel(const float* __restrict__ X,
                                                   const float* __restrict__ g,
                                                   int8_t* __restrict__ Xq,
                                                   float* __restrict__ xs_out) {
    __shared__ float red[256];
    int row = blockIdx.x, tid = threadIdx.x;
    const float* xr = X + (size_t)row * D;
    float xv[8];
    float ss = 0.f;
#pragma unroll
    for (int i = 0; i < 8; i++) { xv[i] = xr[tid + 256 * i]; ss += xv[i] * xv[i]; }
    red[tid] = ss;
    __syncthreads();
    for (int st = 128; st > 0; st >>= 1) {
        if (tid < st) red[tid] += red[tid + st];
        __syncthreads();
    }
    float rstd = 1.0f / sqrtf(red[0] / (float)D + 1e-6f);

    float xn[8];
    float amax = 0.f;
#pragma unroll
    for (int i = 0; i < 8; i++) {
        xn[i] = xv[i] * rstd * g[tid + 256 * i];
        amax = fmaxf(amax, fabsf(xn[i]));
    }
    __syncthreads();
    red[tid] = amax;
    __syncthreads();
    for (int st = 128; st > 0; st >>= 1) {
        if (tid < st) red[tid] = fmaxf(red[tid], red[tid + st]);
        __syncthreads();
    }
    float xs = fmaxf(red[0], 1e-5f);
    float q127 = 127.0f / xs;
#pragma unroll
    for (int i = 0; i < 8; i++) {
        float q = rintf(xn[i] * q127);
        q = fminf(fmaxf(q, -128.f), 127.f);
        Xq[(size_t)row * D + tid + 256 * i] = (int8_t)q;
    }
    if (tid == 0) xs_out[row] = xs;
}

// ---------------- i8 MFMA GEMM: 8-wave blocks, double-buffered LDS ----------
// Restructured from 4-wave 2-barrier (r8): 512 threads, wave owns 16 rows x BN
// (acc[NT] = 32 VGPR), grid 512 blocks -> 2 blocks/CU = 16 waves/CU (was 8).
// Double-buffered staging: one barrier per K-step, prefetch of k+1 overlaps
// MFMA of k (same pattern as attn_mfma_kernel, proven there).
// MODE 0: f32 output. MODE 1: bf16 + fused RoPE (pairs nt, nt+2).
template<int BN, int MODE>
__global__ __launch_bounds__(512, 4) void gemm_i8_mfma(const int8_t* __restrict__ Xq,
                                                       const int8_t* __restrict__ W8,
                                                       void* __restrict__ outp,
                                                       const float* __restrict__ xs,
                                                       const double* __restrict__ wsum, int wi,
                                                       int nw, int O,
                                                       const float* __restrict__ cs,
                                                       const float* __restrict__ sn) {
    constexpr int NT = BN / 16;          // n-tiles per wave (full BN span)
    __shared__ __align__(16) uint8_t As[2][128 * 128];
    __shared__ __align__(16) uint8_t Bs[2][BN * 128];

    const int tid  = threadIdx.x;
    const int lane = tid & 63;
    const int wv   = tid >> 6;           // 0..7
    const int n    = lane & 15, quad = lane >> 4;
    const int row0 = blockIdx.y * 128;
    const int col0 = blockIdx.x * BN;

    i32x4 acc[NT] = {};

    auto stage = [&](int k0, int buf) {
#pragma unroll
        for (int ps = 0; ps < 2; ps++) {             // A tile: 2 passes x 8KB
            int p = ps * 512 + wv * 64 + lane;
            int r = p >> 3, s = p & 7;
            int c = s ^ (r & 7);
            async16(Xq + (size_t)(row0 + r) * D + k0 + c * 16,
                    &As[buf][(ps * 512 + wv * 64) * 16]);
        }
#pragma unroll
        for (int ps = 0; ps < BN / 64; ps++) {       // B tile: BN/64 passes
            int p = ps * 512 + wv * 64 + lane;
            int r = p >> 3, s = p & 7;
            int c = s ^ (r & 7);
            async16(W8 + (size_t)(col0 + r) * D + k0 + c * 16,
                    &Bs[buf][(ps * 512 + wv * 64) * 16]);
        }
    };

    stage(0, 0);
    __syncthreads();

    for (int k0 = 0; k0 < D; k0 += 128) {
        const int cur = (k0 >> 7) & 1;
        if (k0 + 128 < D) stage(k0 + 128, cur ^ 1);
#pragma unroll
        for (int t = 0; t < 2; t++) {
            int r = wv * 16 + n;
            i32x4 af = *(const i32x4*)&As[cur][r * 128 + (((t * 4 + quad) ^ (r & 7)) * 16)];
            i32x4 bfr[NT];
#pragma unroll
            for (int nt = 0; nt < NT; nt++) {
                int rb = nt * 16 + n;
                bfr[nt] = *(const i32x4*)&Bs[cur][rb * 128 + (((t * 4 + quad) ^ (rb & 7)) * 16)];
            }
#pragma unroll
            for (int nt = 0; nt < NT; nt++)
                acc[nt] = __builtin_amdgcn_mfma_i32_16x16x64_i8(af, bfr[nt], acc[nt], 0, 0, 0);
        }
        __syncthreads();   // drains prefetch (vmcnt) + guards buf reuse
    }

    float w = fmaxf((float)(wsum[wi] / (double)nw), 1e-5f);
#pragma unroll
    for (int r2 = 0; r2 < 4; r2++) {
        int row = row0 + wv * 16 + quad * 4 + r2;
        float f = w * xs[row] * (1.0f / 127.0f);
        if (MODE == 0) {
            float* out = (float*)outp;
#pragma unroll
            for (int nt = 0; nt < NT; nt++)
                out[(size_t)row * O + col0 + nt * 16 + n] = (float)acc[nt][r2] * f;
        } else {
            uint16_t* out = (uint16_t*)outp;
            int t = row & (T - 1);
#pragma unroll
            for (int nt = 0; nt < NT; nt++) {
                if ((nt & 3) >= 2) continue;   // rope pair handled at nt, nt+2
                int i = (nt * 16 + n) & 63;
                float a  = (float)acc[nt][r2] * f;
                float bb = (float)acc[nt + 2][r2] * f;
                float c0 = cs[t * HD + i],      s0 = sn[t * HD + i];
                float c1 = cs[t * HD + i + 32], s1 = sn[t * HD + i + 32];
                out[(size_t)row * O + col0 + nt * 16 + n]       = f2bf(a * c0 - bb * s0);
                out[(size_t)row * O + col0 + (nt + 2) * 16 + n] = f2bf(bb * c1 + a * s1);
            }
        }
    }
}

// ---------------- merged k+v projection GEMM (8-wave, dbuf) ----------------
// blockIdx.z: 0 = v-proj (transposed bf16 epilogue), 1 = k-proj (RoPE bf16).
// 512 blocks = 2 blocks/CU = 16 waves/CU. k output must NOT alias Xq_v
// (v blocks read Xq_v concurrently) -- kout lives at vtb + R*OKV (uint16).
__global__ __launch_bounds__(512, 4) void gemm_kv_mfma(const int8_t* __restrict__ Xv,
                                                       const int8_t* __restrict__ Xk,
                                                       const int8_t* __restrict__ Wv8,
                                                       const int8_t* __restrict__ Wk8,
                                                       uint16_t* __restrict__ vt,
                                                       uint16_t* __restrict__ kout,
                                                       const float* __restrict__ xsv,
                                                       const float* __restrict__ xsk,
                                                       const double* __restrict__ wsum,
                                                       const float* __restrict__ cs,
                                                       const float* __restrict__ sn) {
    constexpr int BN = 64, NT = 4;
    __shared__ __align__(16) uint8_t As[2][128 * 128];
    __shared__ __align__(16) uint8_t Bs[2][BN * 128];

    const int z = blockIdx.z;            // 0 = v, 1 = k
    const int8_t* Xq = z ? Xk : Xv;
    const int8_t* W8 = z ? Wk8 : Wv8;
    const float* xs  = z ? xsk : xsv;

    const int tid  = threadIdx.x;
    const int lane = tid & 63;
    const int wv   = tid >> 6;
    const int n    = lane & 15, quad = lane >> 4;
    const int row0 = blockIdx.y * 128;
    const int col0 = blockIdx.x * BN;

    i32x4 acc[NT] = {};

    auto stage = [&](int k0, int buf) {
#pragma unroll
        for (int ps = 0; ps < 2; ps++) {             // A: 2 passes
            int p = ps * 512 + wv * 64 + lane;
            int r = p >> 3, s = p & 7;
            int c = s ^ (r & 7);
            async16(Xq + (size_t)(row0 + r) * D + k0 + c * 16,
                    &As[buf][(ps * 512 + wv * 64) * 16]);
        }
        {                                            // B: 1 pass (64*128 = 8KB)
            int p = wv * 64 + lane;
            int r = p >> 3, s = p & 7;
            int c = s ^ (r & 7);
            async16(W8 + (size_t)(col0 + r) * D + k0 + c * 16,
                    &Bs[buf][(wv * 64) * 16]);
        }
    };

    stage(0, 0);
    __syncthreads();

    for (int k0 = 0; k0 < D; k0 += 128) {
        const int cur = (k0 >> 7) & 1;
        if (k0 + 128 < D) stage(k0 + 128, cur ^ 1);
#pragma unroll
        for (int t = 0; t < 2; t++) {
            int r = wv * 16 + n;
            i32x4 af = *(const i32x4*)&As[cur][r * 128 + (((t * 4 + quad) ^ (r & 7)) * 16)];
            i32x4 bfr[NT];
#pragma unroll
            for (int nt = 0; nt < NT; nt++) {
                int rb = nt * 16 + n;
                bfr[nt] = *(const i32x4*)&Bs[cur][rb * 128 + (((t * 4 + quad) ^ (rb & 7)) * 16)];
            }
#pragma unroll
            for (int nt = 0; nt < NT; nt++)
                acc[nt] = __builtin_amdgcn_mfma_i32_16x16x64_i8(af, bfr[nt], acc[nt], 0, 0, 0);
        }
        __syncthreads();
    }

    float w = fmaxf((float)(wsum[z ? 1 : 2] / (double)(OKV * D)), 1e-5f);
    if (z == 0) {
        // v: transposed bf16 write vt[(b*KVH+kvh)*64+d][t]
        int rowb = row0 + wv * 16 + quad * 4;
        int bb = rowb >> 11;              // rowb / T
        int tb = rowb & (T - 1);
        float fr[4];
#pragma unroll
        for (int r2 = 0; r2 < 4; r2++)
            fr[r2] = w * xs[rowb + r2] * (1.0f / 127.0f);
#pragma unroll
        for (int nt = 0; nt < NT; nt++) {
            int col = col0 + nt * 16 + n;
            int kvh = col >> 6, d = col & 63;
            uint2 w2;
            w2.x = pack_bf16((float)acc[nt][0] * fr[0], (float)acc[nt][1] * fr[1]);
            w2.y = pack_bf16((float)acc[nt][2] * fr[2], (float)acc[nt][3] * fr[3]);
            *(uint2*)(vt + ((size_t)(bb * KVH + kvh) * 64 + d) * T + tb) = w2;
        }
    } else {
        // k: RoPE-fused bf16 write, row-major [row][OKV]
#pragma unroll
        for (int r2 = 0; r2 < 4; r2++) {
            int row = row0 + wv * 16 + quad * 4 + r2;
            float f = w * xs[row] * (1.0f / 127.0f);
            int t = row & (T - 1);
#pragma unroll
            for (int nt = 0; nt < 2; nt++) {   // rope pair (nt, nt+2)
                int i = (nt * 16 + n) & 63;
                float a  = (float)acc[nt][r2] * f;
                float bb = (float)acc[nt + 2][r2] * f;
                float c0 = cs[t * HD + i],      s0 = sn[t * HD + i];
                float c1 = cs[t * HD + i + 32], s1 = sn[t * HD + i + 32];
                kout[(size_t)row * OKV + col0 + nt * 16 + n]       = f2bf(a * c0 - bb * s0);
                kout[(size_t)row * OKV + col0 + (nt + 2) * 16 + n] = f2bf(bb * c1 + a * s1);
            }
        }
    }
}

// ---------------- MFMA flash attention: 8-wave blocks, 2 blocks/CU ----
// grid (8, H, B) = 512 blocks (grid-limited to 2/CU), 512 threads (8 waves).
// Block p handles causal strips p and 15-p; wave wv owns 2 q-tiles:
// {p,15-p}*128 + wv*16. The pairing gives every block exactly
// (2p+2)+(32-2p) = 34 tile-activations over 32-2p staged chunks: balanced
// blocks, 2 tile-computes per staged chunk.
// __launch_bounds__(512, 4): VGPR cap 128. DO NOT raise the min-waves arg --
// (512,6) caps VGPR at ~85 and this structure needs ~90: it spills to scratch
// (r5: FETCH+WRITE 440MB, 173us vs 91us). Grid is 2 blocks/CU anyway, so a
// tighter bound cannot buy occupancy, only spill.
// Register diet keeps VGPR ~60 (no kf/vf arrays, scalar l accumulation).
// Defer-max (T13, THR=8 log2-units) + s_setprio around MFMA clusters (T5).
__global__ __launch_bounds__(512, 4) void attn_mfma_kernel(const uint16_t* __restrict__ qh,
                                                           const uint16_t* __restrict__ kh,
                                                           const uint16_t* __restrict__ vt,
                                                           float* __restrict__ out) {
    __shared__ __align__(16) uint16_t KsB[2][64 * 64];
    __shared__ __align__(16) uint16_t VtB[2][64 * 64];
    __shared__ __align__(16) uint16_t Pw[8][16 * 72];   // per-wave P [q][key] (one tile)

    const int tid  = threadIdx.x;
    const int lane = tid & 63;
    const int wv   = tid >> 6;            // 0..7
    const int p = blockIdx.x, h = blockIdx.y, b = blockIdx.z;
    const int kvh = h >> 2;               // n_rep = 4
    const int n = lane & 15, quad = lane >> 4;
    const float SC = 0.125f * 1.44269504089f;   // score -> log2 units
    const float DEFER = 44.3614f;               // 8 / SC: defer-max threshold (score units)

    // 2 q-tiles per wave: one from strip p (short), one from strip 15-p (long)
    int q_lo[2] = { p * 128 + wv * 16, (15 - p) * 128 + wv * 16 };

    bf16x8 qf[2][2];
#pragma unroll
    for (int i = 0; i < 2; i++) {
        const uint16_t* qp = qh + (size_t)(b * T + q_lo[i] + n) * D + h * HD + quad * 8;
        qf[i][0] = *(const bf16x8*)(qp);
        qf[i][1] = *(const bf16x8*)(qp + 32);
    }

    f32x4 o[2][4] = {};
    float ls[2] = { 0.f, 0.f };
    float m[2] = { -INFINITY, -INFINITY };

    const uint16_t* kbase = kh + (size_t)b * T * OKV + kvh * HD;
    const uint16_t* vbase = vt + (size_t)(b * KVH + kvh) * 64 * T;

    const int nch = 32 - 2 * p;           // chunks for the longer strip (15-p)

    // stage chunk 0 -> buf 0: 512 threads x 16B = exactly one 64x64 bf16 tile each
    {
        int r = tid >> 3, sl = tid & 7;
        int c = sl ^ (r & 7);
        async16(kbase + (size_t)r * OKV + c * 8, &KsB[0][wv * 512]);
        async16(vbase + (size_t)r * T + c * 8,   &VtB[0][wv * 512]);
    }
    __syncthreads();

    for (int ch = 0; ch < nch; ch++) {
        const int cur = ch & 1;
        if (ch + 1 < nch) {   // prefetch next chunk into alternate buffer
            const int t1 = (ch + 1) * 64;
            int r = tid >> 3, sl = tid & 7;
            int c = sl ^ (r & 7);
            async16(kbase + (size_t)(t1 + r) * OKV + c * 8, &KsB[cur ^ 1][wv * 512]);
            async16(vbase + (size_t)r * T + t1 + c * 8,     &VtB[cur ^ 1][wv * 512]);
        }
        const int t0 = ch * 64;
        const uint16_t* Ks = KsB[cur];
        const uint16_t* Vs = VtB[cur];

        // fused per-tile: QK^T -> softmax -> P roundtrip -> PV^T
#pragma unroll
        for (int i = 0; i < 2; i++) {
            if (t0 > q_lo[i] + 15) continue;
            f32x4 sv[4] = {};
            __builtin_amdgcn_s_setprio(1);
#pragma unroll
            for (int ks = 0; ks < 2; ks++)
#pragma unroll
                for (int mt = 0; mt < 4; mt++) {
                    int r = mt * 16 + n;
                    bf16x8 kfr = *(const bf16x8*)&Ks[r * 64 + (((ks * 4 + quad) ^ (n & 7)) * 8)];
                    sv[mt] = __builtin_amdgcn_mfma_f32_16x16x32_bf16(kfr, qf[i][ks], sv[mt], 0, 0, 0);
                }
            __builtin_amdgcn_s_setprio(0);

            const int qg = q_lo[i] + n;
            const bool diag = (t0 + 63 > q_lo[i]);
            if (diag) {        // wave-uniform branch: mask only on diagonal chunks
#pragma unroll
                for (int mt = 0; mt < 4; mt++)
#pragma unroll
                    for (int r2 = 0; r2 < 4; r2++) {
                        int kg = t0 + mt * 16 + quad * 4 + r2;
                        if (kg > qg) sv[mt][r2] = -INFINITY;
                    }
            }
            // row-max via v_max3 tree (15 fmax -> 7 ops)
            float r0 = max3f(sv[0][0], sv[0][1], sv[0][2]);
            float r1 = max3f(sv[0][3], sv[1][0], sv[1][1]);
            float r2m = max3f(sv[1][2], sv[1][3], sv[2][0]);
            float r3 = max3f(sv[2][1], sv[2][2], sv[2][3]);
            float r4 = max3f(sv[3][0], sv[3][1], sv[3][2]);
            float mloc = fmaxf(max3f(max3f(r0, r1, r2m), r3, r4), sv[3][3]);
            mloc = fmaxf(mloc, __shfl_xor(mloc, 16));
            mloc = fmaxf(mloc, __shfl_xor(mloc, 32));
            // defer-max: only pay the rescale pass when the max moved >DEFER.
            // P values then bounded by 2^8; f32 accumulation has ample headroom.
            bool upd = (mloc > m[i] + DEFER);
            if (__ballot(upd)) {
                float mnew = fmaxf(m[i], mloc);
                float corr = fast_exp2((m[i] - mnew) * SC);   // ==1 when unchanged; 0 on first chunk
                m[i] = mnew;
#pragma unroll
                for (int mt = 0; mt < 4; mt++)
#pragma unroll
                    for (int r2 = 0; r2 < 4; r2++) o[i][mt][r2] *= corr;
                ls[i] *= corr;
            }
            float msc = m[i] * SC;
#pragma unroll
            for (int mt = 0; mt < 4; mt++) {
                float pv[4];
#pragma unroll
                for (int r2 = 0; r2 < 4; r2++)
                    pv[r2] = fast_exp2(__builtin_fmaf(sv[mt][r2], SC, -msc));
                ls[i] += (pv[0] + pv[1]) + (pv[2] + pv[3]);
                uint2 w2;
                w2.x = pack_bf16(pv[0], pv[1]);
                w2.y = pack_bf16(pv[2], pv[3]);
                *(uint2*)&Pw[wv][n * 72 + mt * 16 + quad * 4] = w2;
            }
            __builtin_amdgcn_s_setprio(1);
#pragma unroll
            for (int ks = 0; ks < 2; ks++) {
                bf16x8 pf = *(const bf16x8*)&Pw[wv][n * 72 + ks * 32 + quad * 8];
#pragma unroll
                for (int mt = 0; mt < 4; mt++) {
                    int r = mt * 16 + n;
                    bf16x8 vfr = *(const bf16x8*)&Vs[r * 64 + (((ks * 4 + quad) ^ (n & 7)) * 8)];
                    o[i][mt] = __builtin_amdgcn_mfma_f32_16x16x32_bf16(vfr, pf, o[i][mt], 0, 0, 0);
                }
            }
            __builtin_amdgcn_s_setprio(0);
        }
        __syncthreads();   // publish next buffer (prefetch had full compute to land)
    }

#pragma unroll
    for (int i = 0; i < 2; i++) {
        int qg = q_lo[i] + n;
        // l for q-row n lives split across the 4 lanes of the quad group
        float l = ls[i];
        l += __shfl_xor(l, 16);
        l += __shfl_xor(l, 32);
        float inv = 1.0f / l;
#pragma unroll
        for (int mt = 0; mt < 4; mt++) {
            f32x4 ov;
#pragma unroll
            for (int r2 = 0; r2 < 4; r2++) ov[r2] = o[i][mt][r2] * inv;
            *(f32x4*)(out + (size_t)(b * T + qg) * D + h * HD + mt * 16 + quad * 4) = ov;
        }
    }
}

// ---------------- launch ----------------
extern "C" void kernel_launch(void* const* d_in, const int* in_sizes, int n_in,
                              void* d_out, int out_size, void* d_ws, size_t ws_size,
                              hipStream_t stream) {
    const float* x   = (const float*)d_in[0];
    const float* cs  = (const float*)d_in[1];
    const float* sn  = (const float*)d_in[2];
    const float* wq  = (const float*)d_in[3];
    const float* wk  = (const float*)d_in[4];
    const float* wv  = (const float*)d_in[5];
    const float* wo  = (const float*)d_in[6];
    const float* gq  = (const float*)d_in[7];
    const float* gk  = (const float*)d_in[8];
    const float* gv  = (const float*)d_in[9];
    const float* go  = (const float*)d_in[10];
    float* out = (float*)d_out;

    uint8_t* w = (uint8_t*)d_ws;
    double* wsum  = (double*)w;
    float* xs     = (float*)(w + 256);
    size_t off = 256 + 4 * (size_t)R * 4;
    int8_t* Wq8 = (int8_t*)(w + off); off += (size_t)D * D;
    int8_t* Wk8 = (int8_t*)(w + off); off += (size_t)OKV * D;
    int8_t* Wv8 = (int8_t*)(w + off); off += (size_t)OKV * D;
    int8_t* Wo8 = (int8_t*)(w + off); off += (size_t)D * D;
    int8_t* Xq_q = (int8_t*)(w + off); off += (size_t)R * D;
    int8_t* Xq_k = (int8_t*)(w + off); off += (size_t)R * D;
    int8_t* Xq_v = (int8_t*)(w + off); off += (size_t)R * D;
    float* ab = (float*)(w + off); off += (size_t)R * D * 4;      // attention output (f32)
    float* vb = (float*)(w + off); off += (size_t)R * OKV * 4;    // 8MB: vt (4MB) + khb (4MB)
    uint16_t* qhb = (uint16_t*)(w + off); off += (size_t)R * D * 2;
    // vt and k outputs live in the vb region (both written by the merged kv
    // gemm; must NOT alias Xq_k/Xq_v since those are concurrently read).
    // NOTE uint16 element arithmetic: khb = vtb + R*OKV elements = +4MB bytes.
    // (r6 bug: vb + R*OKV in FLOAT units = +8MB = overlapped qhb -> corruption.)
    uint16_t* vtb = (uint16_t*)vb;                  // [0, 4MB)
    uint16_t* khb = vtb + (size_t)R * OKV;          // [4MB, 8MB)
    int8_t*   Aq8 = Xq_q;              // written by rmsq AFTER q-gemm consumed Xq_q

    (void)hipMemsetAsync(wsum, 0, 64, stream);

    absmean4_kernel<<<dim3(256, 4), 256, 0, stream>>>(wq, wk, wv, wo, wsum);
    quantw4_kernel<<<dim3(1024, 4), 256, 0, stream>>>(wq, wk, wv, wo, Wq8, Wk8, Wv8, Wo8, wsum);

    rmsq3_kernel<<<R, 256, 0, stream>>>(x, gq, gk, gv, Xq_q, Xq_k, Xq_v,
                                        xs + 0 * R, xs + 1 * R, xs + 2 * R);

    // q (rope fused, bf16), then merged k+v (v transposed bf16, k rope bf16)
    gemm_i8_mfma<128, 1><<<dim3(D / 128, R / 128), 512, 0, stream>>>(
        Xq_q, Wq8, qhb, xs + 0 * R, wsum, 0, D * D, D, cs, sn);
    gemm_kv_mfma<<<dim3(OKV / 64, R / 128, 2), 512, 0, stream>>>(
        Xq_v, Xq_k, Wv8, Wk8, vtb, khb, xs + 2 * R, xs + 1 * R, wsum, cs, sn);

    attn_mfma_kernel<<<dim3(8, H, B), 512, 0, stream>>>(qhb, khb, vtb, ab);

    rmsq_kernel<<<R, 256, 0, stream>>>(ab, go, Aq8, xs + 3 * R);
    gemm_i8_mfma<128, 0><<<dim3(D / 128, R / 128), 512, 0, stream>>>(
        Aq8, Wo8, out, xs + 3 * R, wsum, 3, D * D, D, cs, sn);
}